// Round 10
// baseline (1139.392 us; speedup 1.0000x reference)
//
#include <hip/hip_runtime.h>
#include <math.h>

#define N_NODES 100000
#define N_EDGES 1600000
#define F_IN 512
#define HD 64                    // H*D = 8*8
#define CC 7
#define NKT (F_IN / 32)                // 16 K-steps for MFMA GEMM1
#define BS 128                         // dst nodes per bucket
#define NBK ((N_NODES + BS - 1) / BS)  // 782 buckets
#define SCHUNK 4096                    // edges per histogram/binscatter block
#define SBLK ((N_EDGES + SCHUNK - 1) / SCHUNK)   // 391 blocks

typedef __attribute__((ext_vector_type(8))) short short8;
typedef __attribute__((ext_vector_type(4))) float f32x4;

// float -> bf16 bits, round-to-nearest-even
__device__ inline unsigned short f2bf(float f) {
    union { float f; unsigned u; } v; v.f = f;
    unsigned u = v.u;
    return (unsigned short)((u + 0x7fffu + ((u >> 16) & 1u)) >> 16);
}
__device__ inline float bf2f(unsigned short b) {
    union { unsigned u; float f; } v; v.u = ((unsigned)b) << 16;
    return v.f;
}

// ---------------- zero bucket counters ----------------
__global__ void zerob_kernel(int* __restrict__ bcnt) {
    int i = threadIdx.x + blockIdx.x * 1024;
    if (i < NBK) bcnt[i] = 0;
}

// ---- W1 -> bf16 in exact B-fragment order: wf[kt][ct][lane][8] ----
__global__ void w1prep_kernel(const float* __restrict__ W1,
                              unsigned short* __restrict__ wf) {
    int t = blockIdx.x * 256 + threadIdx.x;       // [0, NKT*4*64)
    if (t >= NKT * 4 * 64) return;
    int lane = t & 63;
    int ct = (t >> 6) & 3;
    int kt = t >> 8;
    int k0 = kt * 32 + (lane >> 4) * 8;
    int col = ct * 16 + (lane & 15);
    unsigned short* dst = wf + (size_t)t * 8;
    #pragma unroll
    for (int j = 0; j < 8; ++j) dst[j] = f2bf(W1[(k0 + j) * HD + col]);
}

// ------------ GEMM1 (MFMA, no LDS): h1b[N,64](bf16) = x @ W1 --------------
__global__ __launch_bounds__(256) void gemm1_kernel(const float* __restrict__ x,
                                                    const unsigned short* __restrict__ wf,
                                                    unsigned short* __restrict__ h1b) {
    const int wave = threadIdx.x >> 6;
    const int lane = threadIdx.x & 63;
    int arow = blockIdx.x * 64 + wave * 16 + (lane & 15);
    if (arow >= N_NODES) arow = N_NODES - 1;       // clamp for load only
    const float* xp = x + (size_t)arow * F_IN + (lane >> 4) * 8;
    const short8* wp = (const short8*)wf;

    f32x4 acc[4] = {};
    #pragma unroll 4
    for (int kt = 0; kt < NKT; ++kt) {
        f32x4 a0 = *(const f32x4*)(xp + kt * 32);
        f32x4 a1 = *(const f32x4*)(xp + kt * 32 + 4);
        union { short8 s; unsigned short u[8]; } af;
        af.u[0] = f2bf(a0.x); af.u[1] = f2bf(a0.y);
        af.u[2] = f2bf(a0.z); af.u[3] = f2bf(a0.w);
        af.u[4] = f2bf(a1.x); af.u[5] = f2bf(a1.y);
        af.u[6] = f2bf(a1.z); af.u[7] = f2bf(a1.w);
        #pragma unroll
        for (int ct = 0; ct < 4; ++ct) {
            short8 bf = wp[kt * 256 + ct * 64 + lane];
            acc[ct] = __builtin_amdgcn_mfma_f32_16x16x32_bf16(af.s, bf, acc[ct], 0, 0, 0);
        }
    }
    // C/D layout: col = lane&15, row = (lane>>4)*4 + r
    const int orow_base = blockIdx.x * 64 + wave * 16 + (lane >> 4) * 4;
    const int ocol = lane & 15;
    #pragma unroll
    for (int ct = 0; ct < 4; ++ct) {
        #pragma unroll
        for (int r = 0; r < 4; ++r) {
            int orow = orow_base + r;
            if (orow < N_NODES)
                h1b[(size_t)orow * HD + ct * 16 + ocol] = f2bf(acc[ct][r]);
        }
    }
}

// ------------- per-node attention halves, layer 1: [N,8] each -------------
__global__ void att1_kernel(const unsigned short* __restrict__ h1b,
                            const float* __restrict__ a1s, const float* __restrict__ a1d,
                            float* __restrict__ als, float* __restrict__ ald) {
    int tid = blockIdx.x * blockDim.x + threadIdx.x;
    if (tid >= N_NODES * 8) return;
    int n = tid >> 3, h = tid & 7;
    const unsigned short* hp = h1b + (size_t)n * HD + h * 8;
    const float* as = a1s + h * 8;
    const float* ad = a1d + h * 8;
    float s = 0.f, d = 0.f;
    #pragma unroll
    for (int k = 0; k < 8; ++k) { float v = bf2f(hp[k]); s += v * as[k]; d += v * ad[k]; }
    als[tid] = s; ald[tid] = d;
}

// ------- bucket histogram (LDS-aggregated, contention-free) ---------------
__global__ __launch_bounds__(256) void bhist_kernel(const int* __restrict__ ei,
                                                    int* __restrict__ bcnt) {
    __shared__ int cnt[NBK];
    const int e0 = blockIdx.x * SCHUNK;
    int e1 = e0 + SCHUNK; if (e1 > N_EDGES) e1 = N_EDGES;
    for (int b = threadIdx.x; b < NBK; b += 256) cnt[b] = 0;
    __syncthreads();
    for (int i = e0 + threadIdx.x; i < e1; i += 256)
        atomicAdd(&cnt[ei[N_EDGES + i] / BS], 1);
    __syncthreads();
    for (int b = threadIdx.x; b < NBK; b += 256) {
        int c = cnt[b];
        if (c) atomicAdd(&bcnt[b], c);
    }
}

// ------- bucket scan: one 1024-thread block over 782 counts ----------------
__global__ __launch_bounds__(1024) void bscan_kernel(const int* __restrict__ bcnt,
                                                     int* __restrict__ bstart,
                                                     int* __restrict__ bcur) {
    __shared__ int wsum[16];
    const int t = threadIdx.x;
    const int lane = t & 63, w = t >> 6;
    int v = (t < NBK) ? bcnt[t] : 0;
    int x = v;
    #pragma unroll
    for (int o = 1; o < 64; o <<= 1) {
        int u = __shfl_up(x, o, 64);
        if (lane >= o) x += u;
    }
    if (lane == 63) wsum[w] = x;
    __syncthreads();
    if (w == 0) {
        int s = (lane < 16) ? wsum[lane] : 0;
        #pragma unroll
        for (int o = 1; o < 16; o <<= 1) {
            int u = __shfl_up(s, o, 64);
            if (lane >= o) s += u;
        }
        if (lane < 16) wsum[lane] = s;
    }
    __syncthreads();
    int woff = (w > 0) ? wsum[w - 1] : 0;
    int ex = x - v + woff;                 // exclusive prefix
    if (t < NBK) { bstart[t] = ex; bcur[t] = ex; }
    if (t == NBK - 1) bstart[NBK] = ex + v;
}

// --- binscatter: group (src,dst) pairs by dst bucket (LDS-aggregated) ------
__global__ __launch_bounds__(256) void binscatter_kernel(const int* __restrict__ ei,
                                                         int* __restrict__ bcur,
                                                         int2* __restrict__ pairs) {
    __shared__ int cnt[NBK];
    __shared__ int bas[NBK];
    const int e0 = blockIdx.x * SCHUNK;
    int e1 = e0 + SCHUNK; if (e1 > N_EDGES) e1 = N_EDGES;
    for (int b = threadIdx.x; b < NBK; b += 256) cnt[b] = 0;
    __syncthreads();
    for (int i = e0 + threadIdx.x; i < e1; i += 256)
        atomicAdd(&cnt[ei[N_EDGES + i] / BS], 1);
    __syncthreads();
    for (int b = threadIdx.x; b < NBK; b += 256) {
        int c = cnt[b];
        bas[b] = c ? atomicAdd(&bcur[b], c) : 0;
        cnt[b] = 0;                                   // reuse as local cursor
    }
    __syncthreads();
    for (int i = e0 + threadIdx.x; i < e1; i += 256) {
        int s = ei[i];
        int t = ei[N_EDGES + i];
        int b = t / BS;
        int pos = bas[b] + atomicAdd(&cnt[b], 1);
        pairs[pos] = make_int2(s, t);
    }
}

// ---- mega layer 1: per-bucket LDS accumulation + fused epilogue -----------
// block = bucket of 128 dst nodes; LDS acc[128][64] + z[128][8] (36 KB)
__global__ __launch_bounds__(256) void mega1_kernel(
        const int* __restrict__ bstart, const int2* __restrict__ pairs,
        const float* __restrict__ als, const float* __restrict__ ald,
        const unsigned short* __restrict__ h1b, const float* __restrict__ b1,
        const float* __restrict__ W2, const float* __restrict__ a2s,
        const float* __restrict__ a2d,
        unsigned short* __restrict__ g2b, float* __restrict__ al2s,
        float* __restrict__ al2d) {
    __shared__ float acc[BS][HD];     // 32 KB
    __shared__ float zz[BS][8];       // 4 KB
    const int tid = threadIdx.x;
    const int wave = tid >> 6, lane = tid & 63, h = lane >> 3;
    const int n0 = blockIdx.x * BS;
    // zero LDS
    float* af = &acc[0][0];
    for (int i = tid; i < BS * HD; i += 256) af[i] = 0.f;
    float* zf = &zz[0][0];
    for (int i = tid; i < BS * 8; i += 256) zf[i] = 0.f;
    __syncthreads();

    const int es = bstart[blockIdx.x], ee = bstart[blockIdx.x + 1];
    // edge loop: each wave takes 8-edge batches
    for (int j0 = es + wave * 8; j0 < ee; j0 += 32) {
        const int m = ee - j0;                       // >=1
        int pi = j0 + (lane & 7);
        if (pi >= ee) pi = ee - 1;
        int2 pr = pairs[pi];
        #pragma unroll
        for (int q = 0; q < 8; ++q) {
            int s = __shfl(pr.x, q, 64);
            int t = __shfl(pr.y, q, 64);
            float e = als[s * 8 + h] + ald[t * 8 + h];
            e = (e >= 0.f) ? e : 0.2f * e;
            float p = (q < m) ? __expf(e) : 0.f;
            float hv = bf2f(h1b[(size_t)s * HD + lane]);
            atomicAdd(&acc[t - n0][lane], p * hv);
            if ((lane & 7) == 0) atomicAdd(&zz[t - n0][h], p);
        }
    }
    __syncthreads();

    // per-node epilogue: self-loop + normalize + ELU + W2 butterfly + att2
    float w[CC];
    #pragma unroll
    for (int c = 0; c < CC; ++c) w[c] = W2[lane * CC + c];
    for (int n = wave; n < BS; n += 4) {
        int node = n0 + n;
        if (node >= N_NODES) break;
        float e = als[node * 8 + h] + ald[node * 8 + h];
        e = (e >= 0.f) ? e : 0.2f * e;
        float ps = __expf(e);
        float hv = bf2f(h1b[(size_t)node * HD + lane]);
        float a = acc[n][lane] + ps * hv;
        float z = zz[n][h] + ps;
        float v = a / z + b1[lane];
        v = (v > 0.f) ? v : (__expf(v) - 1.f);
        float g[CC];
        #pragma unroll
        for (int c = 0; c < CC; ++c) {
            float r = v * w[c];
            #pragma unroll
            for (int d = 1; d < 64; d <<= 1) r += __shfl_xor(r, d, 64);
            g[c] = r;
        }
        float s2 = 0.f, d2 = 0.f;
        #pragma unroll
        for (int c = 0; c < CC; ++c) { s2 += g[c] * a2s[c]; d2 += g[c] * a2d[c]; }
        if (lane < CC) g2b[(size_t)node * 8 + lane] = f2bf(g[lane]);
        if (lane == CC) g2b[(size_t)node * 8 + CC] = 0;
        if (lane == 8) al2s[node] = s2;
        if (lane == 9) al2d[node] = d2;
    }
}

// ---- mega layer 2: per-bucket LDS accumulation + fused log_softmax --------
// LDS c2[128][8]: cols 0..6 = class accum, col 7 = z
__global__ __launch_bounds__(256) void mega2_kernel(
        const int* __restrict__ bstart, const int2* __restrict__ pairs,
        const float* __restrict__ al2s, const float* __restrict__ al2d,
        const unsigned short* __restrict__ g2b, const float* __restrict__ b2,
        float* __restrict__ out) {
    __shared__ float c2[BS][8];       // 4 KB
    const int tid = threadIdx.x;
    const int wave = tid >> 6, lane = tid & 63;
    const int g = lane >> 3, c = lane & 7;         // 8 edges/wave, lane c = class
    const int n0 = blockIdx.x * BS;
    float* cf = &c2[0][0];
    for (int i = tid; i < BS * 8; i += 256) cf[i] = 0.f;
    __syncthreads();

    const int es = bstart[blockIdx.x], ee = bstart[blockIdx.x + 1];
    for (int j0 = es + wave * 8; j0 < ee; j0 += 32) {
        const int m = ee - j0;
        int pi = j0 + g;
        if (pi >= ee) pi = ee - 1;
        int2 pr = pairs[pi];
        int s = pr.x, t = pr.y;
        float e = al2s[s] + al2d[t];
        e = (e >= 0.f) ? e : 0.2f * e;
        float p = (g < m) ? __expf(e) : 0.f;
        float gv = (c < CC) ? bf2f(g2b[(size_t)s * 8 + c]) : 1.f;   // col 7 -> z
        atomicAdd(&c2[t - n0][c], p * gv);
    }
    __syncthreads();

    // epilogue: 8 lanes per node; self-loop + normalize + log_softmax
    const int grp = tid >> 3;                      // 32 groups
    for (int n = grp; n < BS; n += 32) {
        int node = n0 + n;
        if (node >= N_NODES) break;
        float e = al2s[node] + al2d[node];
        e = (e >= 0.f) ? e : 0.2f * e;
        float ps = __expf(e);
        float gv = (c < CC) ? bf2f(g2b[(size_t)node * 8 + c]) : 1.f;
        float a = c2[n][c] + ps * gv;              // c==7: z + ps
        float z = c2[n][CC == 7 ? 7 : 7] + ps;     // z lane value (same expr for all)
        // broadcast z from lane c==7 of this 8-group via shfl
        z = __shfl(a, 7, 8);
        float o = (c < CC) ? (a / z + b2[c]) : -1e30f;
        float mx = o;
        #pragma unroll
        for (int d = 1; d < 8; d <<= 1) mx = fmaxf(mx, __shfl_xor(mx, d, 8));
        float ex = (c < CC) ? __expf(o - mx) : 0.f;
        float sum = ex;
        #pragma unroll
        for (int d = 1; d < 8; d <<= 1) sum += __shfl_xor(sum, d, 8);
        float lse = mx + __logf(sum);
        if (c < CC) out[(size_t)node * CC + c] = o - lse;
    }
}

extern "C" void kernel_launch(void* const* d_in, const int* in_sizes, int n_in,
                              void* d_out, int out_size, void* d_ws, size_t ws_size,
                              hipStream_t stream) {
    const float* x   = (const float*)d_in[0];
    const int*   ei  = (const int*)d_in[1];
    const float* W1  = (const float*)d_in[2];
    const float* a1s = (const float*)d_in[3];
    const float* a1d = (const float*)d_in[4];
    const float* b1  = (const float*)d_in[5];
    const float* W2  = (const float*)d_in[6];
    const float* a2s = (const float*)d_in[7];
    const float* a2d = (const float*)d_in[8];
    const float* b2  = (const float*)d_in[9];
    float* out = (float*)d_out;

    // byte-offset workspace allocator (64B aligned)
    char* base = (char*)d_ws;
    size_t off = 0;
    auto alloc = [&](size_t bytes) { char* p = base + off; off = (off + bytes + 63) & ~(size_t)63; return p; };
    unsigned short* h1b = (unsigned short*)alloc((size_t)N_NODES * HD * 2);
    unsigned short* wf  = (unsigned short*)alloc((size_t)NKT * 4 * 64 * 8 * 2);
    float* als  = (float*)alloc((size_t)N_NODES * 8 * 4);
    float* ald  = (float*)alloc((size_t)N_NODES * 8 * 4);
    unsigned short* g2b = (unsigned short*)alloc((size_t)N_NODES * 8 * 2);
    float* al2s = (float*)alloc((size_t)N_NODES * 4);
    float* al2d = (float*)alloc((size_t)N_NODES * 4);
    int* bcnt   = (int*)alloc((size_t)NBK * 4);
    int* bstart = (int*)alloc((size_t)(NBK + 1) * 4);
    int* bcur   = (int*)alloc((size_t)NBK * 4);
    int2* pairs = (int2*)alloc((size_t)N_EDGES * 8);

    zerob_kernel<<<1, 1024, 0, stream>>>(bcnt);
    w1prep_kernel<<<(NKT * 4 * 64 + 255) / 256, 256, 0, stream>>>(W1, wf);
    bhist_kernel<<<SBLK, 256, 0, stream>>>(ei, bcnt);
    bscan_kernel<<<1, 1024, 0, stream>>>(bcnt, bstart, bcur);
    binscatter_kernel<<<SBLK, 256, 0, stream>>>(ei, bcur, pairs);

    gemm1_kernel<<<(N_NODES + 63) / 64, 256, 0, stream>>>(x, wf, h1b);
    att1_kernel<<<(N_NODES * 8 + 255) / 256, 256, 0, stream>>>(h1b, a1s, a1d, als, ald);

    mega1_kernel<<<NBK, 256, 0, stream>>>(
        bstart, pairs, als, ald, h1b, b1, W2, a2s, a2d, g2b, al2s, al2d);
    mega2_kernel<<<NBK, 256, 0, stream>>>(
        bstart, pairs, al2s, al2d, g2b, b2, out);
}

// Round 11
// 304.595 us; speedup vs baseline: 3.7407x; 3.7407x over previous
//
#include <hip/hip_runtime.h>
#include <math.h>

#define N_NODES 100000
#define N_EDGES 1600000
#define F_IN 512
#define HD 64                    // H*D = 8*8
#define CC 7
#define NB ((N_NODES + 1023) / 1024)   // 98 scan blocks
#define NKT (F_IN / 32)                // 16 K-steps for MFMA GEMM1
#define NBUCK ((N_NODES + 255) / 256)  // 391 dst buckets (256 nodes each)
#define SCHUNK 4096                    // edges per binscatter block
#define SBLK ((N_EDGES + SCHUNK - 1) / SCHUNK)   // 391 blocks

typedef __attribute__((ext_vector_type(8))) short short8;
typedef __attribute__((ext_vector_type(4))) float f32x4;

// float -> bf16 bits, round-to-nearest-even
__device__ inline unsigned short f2bf(float f) {
    union { float f; unsigned u; } v; v.f = f;
    unsigned u = v.u;
    return (unsigned short)((u + 0x7fffu + ((u >> 16) & 1u)) >> 16);
}
__device__ inline float bf2f(unsigned short b) {
    union { unsigned u; float f; } v; v.u = ((unsigned)b) << 16;
    return v.f;
}

// -------- zero deg (replaces slow hipMemsetAsync fill blit) -------
__global__ void zerodeg_kernel(int* __restrict__ deg) {
    int i = blockIdx.x * 256 + threadIdx.x;
    if (i < N_NODES) deg[i] = 0;
}

// ---- W1 -> bf16 in exact B-fragment order: wf[kt][ct][lane][8] ----
__global__ void w1prep_kernel(const float* __restrict__ W1,
                              unsigned short* __restrict__ wf) {
    int t = blockIdx.x * 256 + threadIdx.x;       // [0, NKT*4*64)
    if (t >= NKT * 4 * 64) return;
    int lane = t & 63;
    int ct = (t >> 6) & 3;
    int kt = t >> 8;
    int k0 = kt * 32 + (lane >> 4) * 8;
    int col = ct * 16 + (lane & 15);
    unsigned short* dst = wf + (size_t)t * 8;
    #pragma unroll
    for (int j = 0; j < 8; ++j) dst[j] = f2bf(W1[(k0 + j) * HD + col]);
}

// ------------ GEMM1 (MFMA, no LDS): h1b[N,64](bf16) = x @ W1 --------------
__global__ __launch_bounds__(256) void gemm1_kernel(const float* __restrict__ x,
                                                    const unsigned short* __restrict__ wf,
                                                    unsigned short* __restrict__ h1b) {
    const int wave = threadIdx.x >> 6;
    const int lane = threadIdx.x & 63;
    int arow = blockIdx.x * 64 + wave * 16 + (lane & 15);
    if (arow >= N_NODES) arow = N_NODES - 1;       // clamp for load only
    const float* xp = x + (size_t)arow * F_IN + (lane >> 4) * 8;
    const short8* wp = (const short8*)wf;

    f32x4 acc[4] = {};
    #pragma unroll 4
    for (int kt = 0; kt < NKT; ++kt) {
        f32x4 a0 = *(const f32x4*)(xp + kt * 32);
        f32x4 a1 = *(const f32x4*)(xp + kt * 32 + 4);
        union { short8 s; unsigned short u[8]; } af;
        af.u[0] = f2bf(a0.x); af.u[1] = f2bf(a0.y);
        af.u[2] = f2bf(a0.z); af.u[3] = f2bf(a0.w);
        af.u[4] = f2bf(a1.x); af.u[5] = f2bf(a1.y);
        af.u[6] = f2bf(a1.z); af.u[7] = f2bf(a1.w);
        #pragma unroll
        for (int ct = 0; ct < 4; ++ct) {
            short8 bf = wp[kt * 256 + ct * 64 + lane];
            acc[ct] = __builtin_amdgcn_mfma_f32_16x16x32_bf16(af.s, bf, acc[ct], 0, 0, 0);
        }
    }
    // C/D layout: col = lane&15, row = (lane>>4)*4 + r
    const int orow_base = blockIdx.x * 64 + wave * 16 + (lane >> 4) * 4;
    const int ocol = lane & 15;
    #pragma unroll
    for (int ct = 0; ct < 4; ++ct) {
        #pragma unroll
        for (int r = 0; r < 4; ++r) {
            int orow = orow_base + r;
            if (orow < N_NODES)
                h1b[(size_t)orow * HD + ct * 16 + ocol] = f2bf(acc[ct][r]);
        }
    }
}

// ------------- per-node attention halves, layer 1: [N,8] each -------------
__global__ void att1_kernel(const unsigned short* __restrict__ h1b,
                            const float* __restrict__ a1s, const float* __restrict__ a1d,
                            float* __restrict__ als, float* __restrict__ ald) {
    int tid = blockIdx.x * blockDim.x + threadIdx.x;
    if (tid >= N_NODES * 8) return;
    int n = tid >> 3, h = tid & 7;
    const unsigned short* hp = h1b + (size_t)n * HD + h * 8;
    const float* as = a1s + h * 8;
    const float* ad = a1d + h * 8;
    float s = 0.f, d = 0.f;
    #pragma unroll
    for (int k = 0; k < 8; ++k) { float v = bf2f(hp[k]); s += v * as[k]; d += v * ad[k]; }
    als[tid] = s; ald[tid] = d;
}

// ----------------------- CSR build: histogram ------------------------------
__global__ void hist_kernel(const int* __restrict__ ei, int* __restrict__ deg) {
    int i = blockIdx.x * blockDim.x + threadIdx.x;
    if (i >= N_EDGES) return;
    atomicAdd(&deg[ei[N_EDGES + i]], 1);
}

// ------- hierarchical scan stage 1: per-block exclusive prefix + bsum ------
__global__ __launch_bounds__(1024) void scan1_kernel(const int* __restrict__ deg,
                                                     int* __restrict__ lp,
                                                     int* __restrict__ bsum) {
    __shared__ int wsum[16];
    const int t = threadIdx.x;
    const int idx = blockIdx.x * 1024 + t;
    const int lane = t & 63, w = t >> 6;
    int d = (idx < N_NODES) ? deg[idx] : 0;
    int x = d;
    #pragma unroll
    for (int o = 1; o < 64; o <<= 1) {
        int v = __shfl_up(x, o, 64);
        if (lane >= o) x += v;
    }
    if (lane == 63) wsum[w] = x;
    __syncthreads();
    if (w == 0) {
        int s = (lane < 16) ? wsum[lane] : 0;
        #pragma unroll
        for (int o = 1; o < 16; o <<= 1) {
            int v = __shfl_up(s, o, 64);
            if (lane >= o) s += v;
        }
        if (lane < 16) wsum[lane] = s;
    }
    __syncthreads();
    int woff = (w > 0) ? wsum[w - 1] : 0;
    if (idx < N_NODES) lp[idx] = x - d + woff;         // exclusive within block
    if (t == 1023) bsum[blockIdx.x] = woff + x;        // block total
}

// ----- scan stage 2: one small block scans the 98 block sums ----------------
__global__ __launch_bounds__(128) void scan2_kernel(const int* __restrict__ bsum,
                                                    int* __restrict__ boff,
                                                    int* __restrict__ rowptr) {
    __shared__ int wt[2];
    const int t = threadIdx.x;
    const int lane = t & 63, w = t >> 6;
    int v = (t < NB) ? bsum[t] : 0;
    int x = v;
    #pragma unroll
    for (int o = 1; o < 64; o <<= 1) {
        int u = __shfl_up(x, o, 64);
        if (lane >= o) x += u;
    }
    if (lane == 63) wt[w] = x;
    __syncthreads();
    int off = (w == 1) ? wt[0] : 0;
    int ex = x - v + off;
    if (t < NB) boff[t] = ex;
    if (t == NB - 1) rowptr[N_NODES] = ex + v;
}

// ---- scan stage 3: add block offsets; write rowptr, cursor, bucket cursors ----
__global__ __launch_bounds__(1024) void scan3_kernel(const int* __restrict__ lp,
                                                     const int* __restrict__ boff,
                                                     int* __restrict__ rowptr,
                                                     int* __restrict__ cursor,
                                                     int* __restrict__ bcur) {
    int idx = blockIdx.x * 1024 + threadIdx.x;
    if (idx >= N_NODES) return;
    int r = lp[idx] + boff[blockIdx.x];
    rowptr[idx] = r;
    cursor[idx] = r;
    if ((idx & 255) == 0) bcur[idx >> 8] = r;          // bucket base = rowptr[b*256]
}

// --- CSR pass A: LDS-aggregated bucket binning (contention-free atomics) ---
__global__ __launch_bounds__(256) void binscatter_kernel(const int* __restrict__ ei,
                                                         int* __restrict__ bcur,
                                                         int2* __restrict__ pairs) {
    __shared__ int cnt[NBUCK];
    __shared__ int bas[NBUCK];
    const int e0 = blockIdx.x * SCHUNK;
    int e1 = e0 + SCHUNK; if (e1 > N_EDGES) e1 = N_EDGES;
    for (int b = threadIdx.x; b < NBUCK; b += 256) cnt[b] = 0;
    __syncthreads();
    for (int i = e0 + threadIdx.x; i < e1; i += 256)
        atomicAdd(&cnt[ei[N_EDGES + i] >> 8], 1);
    __syncthreads();
    for (int b = threadIdx.x; b < NBUCK; b += 256) {
        int c = cnt[b];
        bas[b] = c ? atomicAdd(&bcur[b], c) : 0;
        cnt[b] = 0;                                   // reuse as local cursor
    }
    __syncthreads();
    for (int i = e0 + threadIdx.x; i < e1; i += 256) {
        int s = ei[i];
        int t = ei[N_EDGES + i];
        int b = t >> 8;
        int pos = bas[b] + atomicAdd(&cnt[b], 1);
        pairs[pos] = make_int2(s, t);
    }
}

// --- CSR pass B: finalize within each bucket (L2-resident write window) ----
__global__ __launch_bounds__(256) void finalize_kernel(const int* __restrict__ rowptr,
                                                       const int2* __restrict__ pairs,
                                                       int* __restrict__ cursor,
                                                       int* __restrict__ csr_src) {
    int b = blockIdx.x;
    int n0 = b << 8;
    int n1 = n0 + 256; if (n1 > N_NODES) n1 = N_NODES;
    int rs = rowptr[n0], re = rowptr[n1];
    for (int j = rs + threadIdx.x; j < re; j += 256) {
        int2 p = pairs[j];
        int pos = atomicAdd(&cursor[p.y], 1);
        csr_src[pos] = p.x;
    }
}

// ---- gather layer 1: per-dst wave; inline p, 4-way batched; fused epilogue ---
__global__ __launch_bounds__(256) void gather1_kernel(
        const int* __restrict__ rowptr, const int* __restrict__ csr_src,
        const float* __restrict__ als, const float* __restrict__ ald,
        const unsigned short* __restrict__ h1b, const float* __restrict__ b1,
        const float* __restrict__ W2, const float* __restrict__ a2s,
        const float* __restrict__ a2d,
        unsigned short* __restrict__ g2b, float* __restrict__ al2s,
        float* __restrict__ al2d) {
    int wid = (blockIdx.x * 256 + threadIdx.x) >> 6;     // one wave per dst node
    if (wid >= N_NODES) return;
    const int lane = threadIdx.x & 63;
    const int h = lane >> 3;
    const int rs = rowptr[wid], re = rowptr[wid + 1];
    const float aldt = ald[wid * 8 + h];
    // self loop
    float e = als[wid * 8 + h] + aldt;
    e = (e >= 0.f) ? e : 0.2f * e;
    float p = __expf(e);
    float acc = p * bf2f(h1b[(size_t)wid * HD + lane]);
    float z = p;
    // 4-way batched inline edge loop: 4 independent (als,h1b) chains in flight
    int j = rs;
    for (; j + 4 <= re; j += 4) {
        int s0 = csr_src[j],     s1 = csr_src[j + 1];
        int s2 = csr_src[j + 2], s3 = csr_src[j + 3];
        float e0 = als[s0 * 8 + h] + aldt;
        float e1 = als[s1 * 8 + h] + aldt;
        float e2 = als[s2 * 8 + h] + aldt;
        float e3 = als[s3 * 8 + h] + aldt;
        float v0 = bf2f(h1b[(size_t)s0 * HD + lane]);
        float v1 = bf2f(h1b[(size_t)s1 * HD + lane]);
        float v2 = bf2f(h1b[(size_t)s2 * HD + lane]);
        float v3 = bf2f(h1b[(size_t)s3 * HD + lane]);
        e0 = (e0 >= 0.f) ? e0 : 0.2f * e0;
        e1 = (e1 >= 0.f) ? e1 : 0.2f * e1;
        e2 = (e2 >= 0.f) ? e2 : 0.2f * e2;
        e3 = (e3 >= 0.f) ? e3 : 0.2f * e3;
        float p0 = __expf(e0), p1 = __expf(e1);
        float p2 = __expf(e2), p3 = __expf(e3);
        z += (p0 + p1) + (p2 + p3);
        acc = fmaf(p0, v0, acc);
        acc = fmaf(p1, v1, acc);
        acc = fmaf(p2, v2, acc);
        acc = fmaf(p3, v3, acc);
    }
    for (; j < re; ++j) {
        int s = csr_src[j];
        float e2 = als[s * 8 + h] + aldt;
        e2 = (e2 >= 0.f) ? e2 : 0.2f * e2;
        float p2 = __expf(e2);
        z += p2;
        acc = fmaf(p2, bf2f(h1b[(size_t)s * HD + lane]), acc);
    }
    // epilogue: alpha-normalize + bias + ELU
    float v = acc / z + b1[lane];
    v = (v > 0.f) ? v : (__expf(v) - 1.f);
    // fused GEMM2: g[c] = sum_j v_j * W2[j][c]  (butterfly over the wave)
    float w[CC];
    #pragma unroll
    for (int c = 0; c < CC; ++c) w[c] = W2[lane * CC + c];
    float g[CC];
    #pragma unroll
    for (int c = 0; c < CC; ++c) {
        float r = v * w[c];
        #pragma unroll
        for (int d = 1; d < 64; d <<= 1) r += __shfl_xor(r, d, 64);
        g[c] = r;
    }
    float s2 = 0.f, d2 = 0.f;
    #pragma unroll
    for (int c = 0; c < CC; ++c) { s2 += g[c] * a2s[c]; d2 += g[c] * a2d[c]; }
    if (lane < CC) g2b[(size_t)wid * 8 + lane] = f2bf(g[lane]);
    if (lane == CC) g2b[(size_t)wid * 8 + CC] = 0;
    if (lane == 8) al2s[wid] = s2;
    if (lane == 9) al2d[wid] = d2;
}

// ----- gather layer 2: 8 lanes/node, inline p, 4-way batched, log_softmax ----
__global__ __launch_bounds__(256) void gather2_kernel(
        const int* __restrict__ rowptr, const int* __restrict__ csr_src,
        const float* __restrict__ al2s, const float* __restrict__ al2d,
        const unsigned short* __restrict__ g2b, const float* __restrict__ b2,
        float* __restrict__ out) {
    int gid = blockIdx.x * 256 + threadIdx.x;
    int n = gid >> 3, c = gid & 7;
    if (n >= N_NODES) return;
    const int rs = rowptr[n], re = rowptr[n + 1];
    const float adn = al2d[n];
    float e = al2s[n] + adn;
    e = (e >= 0.f) ? e : 0.2f * e;
    float p = __expf(e);
    float acc = p * bf2f(g2b[(size_t)n * 8 + c]);
    float z = p;
    int j = rs;
    for (; j + 4 <= re; j += 4) {
        int s0 = csr_src[j],     s1 = csr_src[j + 1];
        int s2 = csr_src[j + 2], s3 = csr_src[j + 3];
        float e0 = al2s[s0] + adn;
        float e1 = al2s[s1] + adn;
        float e2 = al2s[s2] + adn;
        float e3 = al2s[s3] + adn;
        float v0 = bf2f(g2b[(size_t)s0 * 8 + c]);
        float v1 = bf2f(g2b[(size_t)s1 * 8 + c]);
        float v2 = bf2f(g2b[(size_t)s2 * 8 + c]);
        float v3 = bf2f(g2b[(size_t)s3 * 8 + c]);
        e0 = (e0 >= 0.f) ? e0 : 0.2f * e0;
        e1 = (e1 >= 0.f) ? e1 : 0.2f * e1;
        e2 = (e2 >= 0.f) ? e2 : 0.2f * e2;
        e3 = (e3 >= 0.f) ? e3 : 0.2f * e3;
        float p0 = __expf(e0), p1 = __expf(e1);
        float p2 = __expf(e2), p3 = __expf(e3);
        z += (p0 + p1) + (p2 + p3);
        acc = fmaf(p0, v0, acc);
        acc = fmaf(p1, v1, acc);
        acc = fmaf(p2, v2, acc);
        acc = fmaf(p3, v3, acc);
    }
    for (; j < re; ++j) {
        int s = csr_src[j];
        float e2 = al2s[s] + adn;
        e2 = (e2 >= 0.f) ? e2 : 0.2f * e2;
        float p2 = __expf(e2);
        z += p2;
        acc = fmaf(p2, bf2f(g2b[(size_t)s * 8 + c]), acc);
    }
    float o = (c < CC) ? (acc / z + b2[c]) : -1e30f;
    float m = o;
    #pragma unroll
    for (int d = 1; d < 8; d <<= 1) m = fmaxf(m, __shfl_xor(m, d, 8));
    float ex = (c < CC) ? __expf(o - m) : 0.f;
    float sum = ex;
    #pragma unroll
    for (int d = 1; d < 8; d <<= 1) sum += __shfl_xor(sum, d, 8);
    float lse = m + __logf(sum);
    if (c < CC) out[(size_t)n * CC + c] = o - lse;
}

extern "C" void kernel_launch(void* const* d_in, const int* in_sizes, int n_in,
                              void* d_out, int out_size, void* d_ws, size_t ws_size,
                              hipStream_t stream) {
    const float* x   = (const float*)d_in[0];
    const int*   ei  = (const int*)d_in[1];
    const float* W1  = (const float*)d_in[2];
    const float* a1s = (const float*)d_in[3];
    const float* a1d = (const float*)d_in[4];
    const float* b1  = (const float*)d_in[5];
    const float* W2  = (const float*)d_in[6];
    const float* a2s = (const float*)d_in[7];
    const float* a2d = (const float*)d_in[8];
    const float* b2  = (const float*)d_in[9];
    float* out = (float*)d_out;

    // byte-offset workspace allocator (64B aligned)
    char* base = (char*)d_ws;
    size_t off = 0;
    auto alloc = [&](size_t bytes) { char* p = base + off; off = (off + bytes + 63) & ~(size_t)63; return p; };
    unsigned short* h1b = (unsigned short*)alloc((size_t)N_NODES * HD * 2);
    unsigned short* wf  = (unsigned short*)alloc((size_t)NKT * 4 * 64 * 8 * 2);
    float* als  = (float*)alloc((size_t)N_NODES * 8 * 4);
    float* ald  = (float*)alloc((size_t)N_NODES * 8 * 4);
    unsigned short* g2b = (unsigned short*)alloc((size_t)N_NODES * 8 * 2);
    float* al2s = (float*)alloc((size_t)N_NODES * 4);
    float* al2d = (float*)alloc((size_t)N_NODES * 4);
    int* rowptr = (int*)alloc((size_t)(N_NODES + 1) * 4);
    int* cursor = (int*)alloc((size_t)N_NODES * 4);
    int* deg    = (int*)alloc((size_t)N_NODES * 4);
    int* lp     = (int*)alloc((size_t)N_NODES * 4);
    int* bsum   = (int*)alloc((size_t)NB * 4);
    int* boff   = (int*)alloc((size_t)NB * 4);
    int* bcur   = (int*)alloc((size_t)NBUCK * 4);
    int2* pairs = (int2*)alloc((size_t)N_EDGES * 8);
    int* csr_src= (int*)alloc((size_t)N_EDGES * 4);

    zerodeg_kernel<<<(N_NODES + 255) / 256, 256, 0, stream>>>(deg);
    w1prep_kernel<<<(NKT * 4 * 64 + 255) / 256, 256, 0, stream>>>(W1, wf);
    hist_kernel<<<(N_EDGES + 255) / 256, 256, 0, stream>>>(ei, deg);
    scan1_kernel<<<NB, 1024, 0, stream>>>(deg, lp, bsum);
    scan2_kernel<<<1, 128, 0, stream>>>(bsum, boff, rowptr);
    scan3_kernel<<<NB, 1024, 0, stream>>>(lp, boff, rowptr, cursor, bcur);
    binscatter_kernel<<<SBLK, 256, 0, stream>>>(ei, bcur, pairs);

    gemm1_kernel<<<(N_NODES + 63) / 64, 256, 0, stream>>>(x, wf, h1b);
    att1_kernel<<<(N_NODES * 8 + 255) / 256, 256, 0, stream>>>(h1b, a1s, a1d, als, ald);

    finalize_kernel<<<NBUCK, 256, 0, stream>>>(rowptr, pairs, cursor, csr_src);

    const int gblk = (N_NODES * 64 + 255) / 256;
    gather1_kernel<<<gblk, 256, 0, stream>>>(
        rowptr, csr_src, als, ald, h1b, b1, W2, a2s, a2d, g2b, al2s, al2d);
    gather2_kernel<<<(N_NODES * 8 + 255) / 256, 256, 0, stream>>>(
        rowptr, csr_src, al2s, al2d, g2b, b2, out);
}

// Round 12
// 242.313 us; speedup vs baseline: 4.7021x; 1.2570x over previous
//
#include <hip/hip_runtime.h>
#include <math.h>

#define N_NODES 100000
#define N_EDGES 1600000
#define F_IN 512
#define HD 64                    // H*D = 8*8
#define CC 7
#define NKT (F_IN / 32)                // 16 K-steps for MFMA GEMM1
#define BS 128                         // dst nodes per bucket
#define NBK ((N_NODES + BS - 1) / BS)  // 782 buckets
#define ECAP 4096                      // LDS edge capacity per bucket (mean 2048, +45 sigma)
#define SCHUNK 4096                    // edges per histogram/binscatter block
#define SBLK ((N_EDGES + SCHUNK - 1) / SCHUNK)   // 391 blocks

typedef __attribute__((ext_vector_type(8))) short short8;
typedef __attribute__((ext_vector_type(4))) float f32x4;

// float -> bf16 bits, round-to-nearest-even
__device__ inline unsigned short f2bf(float f) {
    union { float f; unsigned u; } v; v.f = f;
    unsigned u = v.u;
    return (unsigned short)((u + 0x7fffu + ((u >> 16) & 1u)) >> 16);
}
__device__ inline float bf2f(unsigned short b) {
    union { unsigned u; float f; } v; v.u = ((unsigned)b) << 16;
    return v.f;
}

// ---------------- zero bucket counters ----------------
__global__ void zerob_kernel(int* __restrict__ bcnt) {
    int i = threadIdx.x;
    if (i < NBK) bcnt[i] = 0;
}

// ---- W1 -> bf16 in exact B-fragment order: wf[kt][ct][lane][8] ----
__global__ void w1prep_kernel(const float* __restrict__ W1,
                              unsigned short* __restrict__ wf) {
    int t = blockIdx.x * 256 + threadIdx.x;       // [0, NKT*4*64)
    if (t >= NKT * 4 * 64) return;
    int lane = t & 63;
    int ct = (t >> 6) & 3;
    int kt = t >> 8;
    int k0 = kt * 32 + (lane >> 4) * 8;
    int col = ct * 16 + (lane & 15);
    unsigned short* dst = wf + (size_t)t * 8;
    #pragma unroll
    for (int j = 0; j < 8; ++j) dst[j] = f2bf(W1[(k0 + j) * HD + col]);
}

// --- GEMM1 (MFMA) + fused att1: h1b[N,64](bf16), als/ald[N,8] --------------
__global__ __launch_bounds__(256) void gemm1att_kernel(const float* __restrict__ x,
                                                       const unsigned short* __restrict__ wf,
                                                       const float* __restrict__ a1s,
                                                       const float* __restrict__ a1d,
                                                       unsigned short* __restrict__ h1b,
                                                       float* __restrict__ als,
                                                       float* __restrict__ ald) {
    __shared__ float ls[64][65];                   // f32 h stage for att halves
    const int wave = threadIdx.x >> 6;
    const int lane = threadIdx.x & 63;
    int arow = blockIdx.x * 64 + wave * 16 + (lane & 15);
    if (arow >= N_NODES) arow = N_NODES - 1;       // clamp for load only
    const float* xp = x + (size_t)arow * F_IN + (lane >> 4) * 8;
    const short8* wp = (const short8*)wf;

    f32x4 acc[4] = {};
    #pragma unroll 4
    for (int kt = 0; kt < NKT; ++kt) {
        f32x4 a0 = *(const f32x4*)(xp + kt * 32);
        f32x4 a1 = *(const f32x4*)(xp + kt * 32 + 4);
        union { short8 s; unsigned short u[8]; } af;
        af.u[0] = f2bf(a0.x); af.u[1] = f2bf(a0.y);
        af.u[2] = f2bf(a0.z); af.u[3] = f2bf(a0.w);
        af.u[4] = f2bf(a1.x); af.u[5] = f2bf(a1.y);
        af.u[6] = f2bf(a1.z); af.u[7] = f2bf(a1.w);
        #pragma unroll
        for (int ct = 0; ct < 4; ++ct) {
            short8 bf = wp[kt * 256 + ct * 64 + lane];
            acc[ct] = __builtin_amdgcn_mfma_f32_16x16x32_bf16(af.s, bf, acc[ct], 0, 0, 0);
        }
    }
    // C/D layout: col = lane&15, row = (lane>>4)*4 + r
    const int lrow_base = wave * 16 + (lane >> 4) * 4;
    const int ocol = lane & 15;
    #pragma unroll
    for (int ct = 0; ct < 4; ++ct) {
        #pragma unroll
        for (int r = 0; r < 4; ++r) {
            int lrow = lrow_base + r;
            int orow = blockIdx.x * 64 + lrow;
            ls[lrow][ct * 16 + ocol] = acc[ct][r];
            if (orow < N_NODES)
                h1b[(size_t)orow * HD + ct * 16 + ocol] = f2bf(acc[ct][r]);
        }
    }
    __syncthreads();
    // attention halves: 512 (row,head) tasks over 256 threads
    #pragma unroll
    for (int task = threadIdx.x; task < 64 * 8; task += 256) {
        int r = task >> 3, h = task & 7;
        int node = blockIdx.x * 64 + r;
        if (node < N_NODES) {
            float s = 0.f, d = 0.f;
            #pragma unroll
            for (int k = 0; k < 8; ++k) {
                float v = ls[r][h * 8 + k];
                s += v * a1s[h * 8 + k];
                d += v * a1d[h * 8 + k];
            }
            als[node * 8 + h] = s;
            ald[node * 8 + h] = d;
        }
    }
}

// ------- bucket histogram (LDS-aggregated, contention-free) ---------------
__global__ __launch_bounds__(256) void bhist_kernel(const int* __restrict__ ei,
                                                    int* __restrict__ bcnt) {
    __shared__ int cnt[NBK];
    const int e0 = blockIdx.x * SCHUNK;
    int e1 = e0 + SCHUNK; if (e1 > N_EDGES) e1 = N_EDGES;
    for (int b = threadIdx.x; b < NBK; b += 256) cnt[b] = 0;
    __syncthreads();
    for (int i = e0 + threadIdx.x; i < e1; i += 256)
        atomicAdd(&cnt[ei[N_EDGES + i] >> 7], 1);
    __syncthreads();
    for (int b = threadIdx.x; b < NBK; b += 256) {
        int c = cnt[b];
        if (c) atomicAdd(&bcnt[b], c);
    }
}

// ------- bucket scan: one 1024-thread block over 782 counts ----------------
__global__ __launch_bounds__(1024) void bscan_kernel(const int* __restrict__ bcnt,
                                                     int* __restrict__ bstart,
                                                     int* __restrict__ bcur) {
    __shared__ int wsum[16];
    const int t = threadIdx.x;
    const int lane = t & 63, w = t >> 6;
    int v = (t < NBK) ? bcnt[t] : 0;
    int x = v;
    #pragma unroll
    for (int o = 1; o < 64; o <<= 1) {
        int u = __shfl_up(x, o, 64);
        if (lane >= o) x += u;
    }
    if (lane == 63) wsum[w] = x;
    __syncthreads();
    if (w == 0) {
        int s = (lane < 16) ? wsum[lane] : 0;
        #pragma unroll
        for (int o = 1; o < 16; o <<= 1) {
            int u = __shfl_up(s, o, 64);
            if (lane >= o) s += u;
        }
        if (lane < 16) wsum[lane] = s;
    }
    __syncthreads();
    int woff = (w > 0) ? wsum[w - 1] : 0;
    int ex = x - v + woff;                 // exclusive prefix
    if (t < NBK) { bstart[t] = ex; bcur[t] = ex; }
    if (t == NBK - 1) bstart[NBK] = ex + v;
}

// --- binscatter: group (src,dst) pairs by dst bucket (LDS-aggregated) ------
__global__ __launch_bounds__(256) void binscatter_kernel(const int* __restrict__ ei,
                                                         int* __restrict__ bcur,
                                                         int2* __restrict__ pairs) {
    __shared__ int cnt[NBK];
    __shared__ int bas[NBK];
    const int e0 = blockIdx.x * SCHUNK;
    int e1 = e0 + SCHUNK; if (e1 > N_EDGES) e1 = N_EDGES;
    for (int b = threadIdx.x; b < NBK; b += 256) cnt[b] = 0;
    __syncthreads();
    for (int i = e0 + threadIdx.x; i < e1; i += 256)
        atomicAdd(&cnt[ei[N_EDGES + i] >> 7], 1);
    __syncthreads();
    for (int b = threadIdx.x; b < NBK; b += 256) {
        int c = cnt[b];
        bas[b] = c ? atomicAdd(&bcur[b], c) : 0;
        cnt[b] = 0;                                   // reuse as local cursor
    }
    __syncthreads();
    for (int i = e0 + threadIdx.x; i < e1; i += 256) {
        int s = ei[i];
        int t = ei[N_EDGES + i];
        int b = t >> 7;
        int pos = bas[b] + atomicAdd(&cnt[b], 1);
        pairs[pos] = make_int2(s, t);
    }
}

// ---- gather layer 1: per-bucket block, LDS counting sort + reg gather -------
// 512 threads = 8 waves; wave w handles nodes [w*16, w*16+16) of the bucket.
__global__ __launch_bounds__(512) void gather1_kernel(
        const int* __restrict__ bstart, const int2* __restrict__ pairs,
        const float* __restrict__ als, const float* __restrict__ ald,
        const unsigned short* __restrict__ h1b, const float* __restrict__ b1,
        const float* __restrict__ W2, const float* __restrict__ a2s,
        const float* __restrict__ a2d,
        unsigned short* __restrict__ g2b, float* __restrict__ al2s,
        float* __restrict__ al2d) {
    __shared__ int cnt[BS];
    __shared__ int start[BS];
    __shared__ int srcl[ECAP];
    const int tid = threadIdx.x;
    const int wave = tid >> 6, lane = tid & 63, h = lane >> 3;
    const int n0 = blockIdx.x * BS;
    const int es = bstart[blockIdx.x];
    const int ne = bstart[blockIdx.x + 1] - es;
    if (tid < BS) cnt[tid] = 0;
    __syncthreads();
    // count per node
    for (int k = tid; k < ne; k += 512)
        atomicAdd(&cnt[pairs[es + k].y & (BS - 1)], 1);
    __syncthreads();
    // exclusive scan of 128 counts by wave 0 (two 64-lane scans)
    if (tid < 64) {
        int a = cnt[lane], b = cnt[64 + lane];
        int xx = a;
        #pragma unroll
        for (int o = 1; o < 64; o <<= 1) { int u = __shfl_up(xx, o, 64); if (lane >= o) xx += u; }
        int totalA = __shfl(xx, 63, 64);
        int yy = b;
        #pragma unroll
        for (int o = 1; o < 64; o <<= 1) { int u = __shfl_up(yy, o, 64); if (lane >= o) yy += u; }
        start[lane] = xx - a;
        start[64 + lane] = totalA + yy - b;
        cnt[lane] = 0; cnt[64 + lane] = 0;            // reuse as cursors
    }
    __syncthreads();
    // place src ids per node
    for (int k = tid; k < ne; k += 512) {
        int2 pr = pairs[es + k];
        int ln = pr.y & (BS - 1);
        int pos = start[ln] + atomicAdd(&cnt[ln], 1);
        if (pos < ECAP) srcl[pos] = pr.x;
    }
    __syncthreads();

    // per-node gather with 4-way batched inline-p loop
    float w[CC];
    #pragma unroll
    for (int c = 0; c < CC; ++c) w[c] = W2[lane * CC + c];
    for (int n = wave * 16; n < wave * 16 + 16; ++n) {
        int node = n0 + n;
        if (node >= N_NODES) break;
        const float aldt = ald[node * 8 + h];
        float e = als[node * 8 + h] + aldt;            // self loop
        e = (e >= 0.f) ? e : 0.2f * e;
        float p = __expf(e);
        float acc = p * bf2f(h1b[(size_t)node * HD + lane]);
        float z = p;
        int k = start[n];
        int ke = k + cnt[n]; if (ke > ECAP) ke = ECAP;
        for (; k + 4 <= ke; k += 4) {
            int s0 = srcl[k],     s1 = srcl[k + 1];
            int s2 = srcl[k + 2], s3 = srcl[k + 3];
            float e0 = als[s0 * 8 + h] + aldt;
            float e1 = als[s1 * 8 + h] + aldt;
            float e2 = als[s2 * 8 + h] + aldt;
            float e3 = als[s3 * 8 + h] + aldt;
            float v0 = bf2f(h1b[(size_t)s0 * HD + lane]);
            float v1 = bf2f(h1b[(size_t)s1 * HD + lane]);
            float v2 = bf2f(h1b[(size_t)s2 * HD + lane]);
            float v3 = bf2f(h1b[(size_t)s3 * HD + lane]);
            e0 = (e0 >= 0.f) ? e0 : 0.2f * e0;
            e1 = (e1 >= 0.f) ? e1 : 0.2f * e1;
            e2 = (e2 >= 0.f) ? e2 : 0.2f * e2;
            e3 = (e3 >= 0.f) ? e3 : 0.2f * e3;
            float p0 = __expf(e0), p1 = __expf(e1);
            float p2 = __expf(e2), p3 = __expf(e3);
            z += (p0 + p1) + (p2 + p3);
            acc = fmaf(p0, v0, acc);
            acc = fmaf(p1, v1, acc);
            acc = fmaf(p2, v2, acc);
            acc = fmaf(p3, v3, acc);
        }
        for (; k < ke; ++k) {
            int s = srcl[k];
            float e2 = als[s * 8 + h] + aldt;
            e2 = (e2 >= 0.f) ? e2 : 0.2f * e2;
            float p2 = __expf(e2);
            z += p2;
            acc = fmaf(p2, bf2f(h1b[(size_t)s * HD + lane]), acc);
        }
        // epilogue: alpha-normalize + bias + ELU
        float v = acc / z + b1[lane];
        v = (v > 0.f) ? v : (__expf(v) - 1.f);
        // fused GEMM2: g[c] = sum_j v_j * W2[j][c]  (butterfly over the wave)
        float g[CC];
        #pragma unroll
        for (int c = 0; c < CC; ++c) {
            float r = v * w[c];
            #pragma unroll
            for (int d = 1; d < 64; d <<= 1) r += __shfl_xor(r, d, 64);
            g[c] = r;
        }
        float s2 = 0.f, d2 = 0.f;
        #pragma unroll
        for (int c = 0; c < CC; ++c) { s2 += g[c] * a2s[c]; d2 += g[c] * a2d[c]; }
        if (lane < CC) g2b[(size_t)node * 8 + lane] = f2bf(g[lane]);
        if (lane == CC) g2b[(size_t)node * 8 + CC] = 0;
        if (lane == 8) al2s[node] = s2;
        if (lane == 9) al2d[node] = d2;
    }
}

// ---- gather layer 2: per-bucket block, LDS sort + 8-lane/node log_softmax ---
__global__ __launch_bounds__(256) void gather2_kernel(
        const int* __restrict__ bstart, const int2* __restrict__ pairs,
        const float* __restrict__ al2s, const float* __restrict__ al2d,
        const unsigned short* __restrict__ g2b, const float* __restrict__ b2,
        float* __restrict__ out) {
    __shared__ int cnt[BS];
    __shared__ int start[BS];
    __shared__ int srcl[ECAP];
    const int tid = threadIdx.x;
    const int lane = tid & 63;
    const int grp = tid >> 3, c = tid & 7;         // 32 groups of 8 lanes
    const int n0 = blockIdx.x * BS;
    const int es = bstart[blockIdx.x];
    const int ne = bstart[blockIdx.x + 1] - es;
    if (tid < BS) cnt[tid] = 0;
    __syncthreads();
    for (int k = tid; k < ne; k += 256)
        atomicAdd(&cnt[pairs[es + k].y & (BS - 1)], 1);
    __syncthreads();
    if (tid < 64) {
        int a = cnt[lane], b = cnt[64 + lane];
        int xx = a;
        #pragma unroll
        for (int o = 1; o < 64; o <<= 1) { int u = __shfl_up(xx, o, 64); if (lane >= o) xx += u; }
        int totalA = __shfl(xx, 63, 64);
        int yy = b;
        #pragma unroll
        for (int o = 1; o < 64; o <<= 1) { int u = __shfl_up(yy, o, 64); if (lane >= o) yy += u; }
        start[lane] = xx - a;
        start[64 + lane] = totalA + yy - b;
        cnt[lane] = 0; cnt[64 + lane] = 0;
    }
    __syncthreads();
    for (int k = tid; k < ne; k += 256) {
        int2 pr = pairs[es + k];
        int ln = pr.y & (BS - 1);
        int pos = start[ln] + atomicAdd(&cnt[ln], 1);
        if (pos < ECAP) srcl[pos] = pr.x;
    }
    __syncthreads();

    for (int n = grp * 4; n < grp * 4 + 4; ++n) {
        int node = n0 + n;
        if (node >= N_NODES) break;
        const float adn = al2d[node];
        float e = al2s[node] + adn;                    // self loop
        e = (e >= 0.f) ? e : 0.2f * e;
        float p = __expf(e);
        float acc = p * bf2f(g2b[(size_t)node * 8 + c]);
        float z = p;
        int k = start[n];
        int ke = k + cnt[n]; if (ke > ECAP) ke = ECAP;
        for (; k + 4 <= ke; k += 4) {
            int s0 = srcl[k],     s1 = srcl[k + 1];
            int s2 = srcl[k + 2], s3 = srcl[k + 3];
            float e0 = al2s[s0] + adn;
            float e1 = al2s[s1] + adn;
            float e2 = al2s[s2] + adn;
            float e3 = al2s[s3] + adn;
            float v0 = bf2f(g2b[(size_t)s0 * 8 + c]);
            float v1 = bf2f(g2b[(size_t)s1 * 8 + c]);
            float v2 = bf2f(g2b[(size_t)s2 * 8 + c]);
            float v3 = bf2f(g2b[(size_t)s3 * 8 + c]);
            e0 = (e0 >= 0.f) ? e0 : 0.2f * e0;
            e1 = (e1 >= 0.f) ? e1 : 0.2f * e1;
            e2 = (e2 >= 0.f) ? e2 : 0.2f * e2;
            e3 = (e3 >= 0.f) ? e3 : 0.2f * e3;
            float p0 = __expf(e0), p1 = __expf(e1);
            float p2 = __expf(e2), p3 = __expf(e3);
            z += (p0 + p1) + (p2 + p3);
            acc = fmaf(p0, v0, acc);
            acc = fmaf(p1, v1, acc);
            acc = fmaf(p2, v2, acc);
            acc = fmaf(p3, v3, acc);
        }
        for (; k < ke; ++k) {
            int s = srcl[k];
            float e2 = al2s[s] + adn;
            e2 = (e2 >= 0.f) ? e2 : 0.2f * e2;
            float p2 = __expf(e2);
            z += p2;
            acc = fmaf(p2, bf2f(g2b[(size_t)s * 8 + c]), acc);
        }
        float o = (c < CC) ? (acc / z + b2[c]) : -1e30f;
        float m = o;
        #pragma unroll
        for (int d = 1; d < 8; d <<= 1) m = fmaxf(m, __shfl_xor(m, d, 8));
        float ex = (c < CC) ? __expf(o - m) : 0.f;
        float sum = ex;
        #pragma unroll
        for (int d = 1; d < 8; d <<= 1) sum += __shfl_xor(sum, d, 8);
        float lse = m + __logf(sum);
        if (c < CC) out[(size_t)node * CC + c] = o - lse;
    }
}

extern "C" void kernel_launch(void* const* d_in, const int* in_sizes, int n_in,
                              void* d_out, int out_size, void* d_ws, size_t ws_size,
                              hipStream_t stream) {
    const float* x   = (const float*)d_in[0];
    const int*   ei  = (const int*)d_in[1];
    const float* W1  = (const float*)d_in[2];
    const float* a1s = (const float*)d_in[3];
    const float* a1d = (const float*)d_in[4];
    const float* b1  = (const float*)d_in[5];
    const float* W2  = (const float*)d_in[6];
    const float* a2s = (const float*)d_in[7];
    const float* a2d = (const float*)d_in[8];
    const float* b2  = (const float*)d_in[9];
    float* out = (float*)d_out;

    // byte-offset workspace allocator (64B aligned)
    char* base = (char*)d_ws;
    size_t off = 0;
    auto alloc = [&](size_t bytes) { char* p = base + off; off = (off + bytes + 63) & ~(size_t)63; return p; };
    unsigned short* h1b = (unsigned short*)alloc((size_t)N_NODES * HD * 2);
    unsigned short* wf  = (unsigned short*)alloc((size_t)NKT * 4 * 64 * 8 * 2);
    float* als  = (float*)alloc((size_t)N_NODES * 8 * 4);
    float* ald  = (float*)alloc((size_t)N_NODES * 8 * 4);
    unsigned short* g2b = (unsigned short*)alloc((size_t)N_NODES * 8 * 2);
    float* al2s = (float*)alloc((size_t)N_NODES * 4);
    float* al2d = (float*)alloc((size_t)N_NODES * 4);
    int* bcnt   = (int*)alloc((size_t)NBK * 4);
    int* bstart = (int*)alloc((size_t)(NBK + 1) * 4);
    int* bcur   = (int*)alloc((size_t)NBK * 4);
    int2* pairs = (int2*)alloc((size_t)N_EDGES * 8);

    zerob_kernel<<<1, 1024, 0, stream>>>(bcnt);
    w1prep_kernel<<<(NKT * 4 * 64 + 255) / 256, 256, 0, stream>>>(W1, wf);
    bhist_kernel<<<SBLK, 256, 0, stream>>>(ei, bcnt);
    bscan_kernel<<<1, 1024, 0, stream>>>(bcnt, bstart, bcur);
    binscatter_kernel<<<SBLK, 256, 0, stream>>>(ei, bcur, pairs);

    gemm1att_kernel<<<(N_NODES + 63) / 64, 256, 0, stream>>>(
        x, wf, a1s, a1d, h1b, als, ald);

    gather1_kernel<<<NBK, 512, 0, stream>>>(
        bstart, pairs, als, ald, h1b, b1, W2, a2s, a2d, g2b, al2s, al2d);
    gather2_kernel<<<NBK, 256, 0, stream>>>(
        bstart, pairs, al2s, al2d, g2b, b2, out);
}

// Round 13
// 242.114 us; speedup vs baseline: 4.7060x; 1.0008x over previous
//
#include <hip/hip_runtime.h>
#include <math.h>

#define N_NODES 100000
#define N_EDGES 1600000
#define F_IN 512
#define HD 64                    // H*D = 8*8
#define CC 7
#define NKT (F_IN / 32)                // 16 K-steps for MFMA GEMM1
#define BS 128                         // dst nodes per bucket
#define NBK ((N_NODES + BS - 1) / BS)  // 782 buckets
#define ECAP 4096                      // fixed edge capacity per bucket (mean 2048)
#define SCHUNK 4096                    // edges per binscatter block
#define SBLK ((N_EDGES + SCHUNK - 1) / SCHUNK)   // 391 blocks

typedef __attribute__((ext_vector_type(8))) short short8;
typedef __attribute__((ext_vector_type(4))) float f32x4;

// float -> bf16 bits, round-to-nearest-even
__device__ inline unsigned short f2bf(float f) {
    union { float f; unsigned u; } v; v.f = f;
    unsigned u = v.u;
    return (unsigned short)((u + 0x7fffu + ((u >> 16) & 1u)) >> 16);
}
__device__ inline float bf2f(unsigned short b) {
    union { unsigned u; float f; } v; v.u = ((unsigned)b) << 16;
    return v.f;
}

// ---------------- zero bucket cursors ----------------
__global__ void zerob_kernel(int* __restrict__ bcur) {
    int i = threadIdx.x;
    if (i < NBK) bcur[i] = 0;
}

// ---- W1 -> bf16 in exact B-fragment order: wf[kt][ct][lane][8] ----
__global__ void w1prep_kernel(const float* __restrict__ W1,
                              unsigned short* __restrict__ wf) {
    int t = blockIdx.x * 256 + threadIdx.x;       // [0, NKT*4*64)
    if (t >= NKT * 4 * 64) return;
    int lane = t & 63;
    int ct = (t >> 6) & 3;
    int kt = t >> 8;
    int k0 = kt * 32 + (lane >> 4) * 8;
    int col = ct * 16 + (lane & 15);
    unsigned short* dst = wf + (size_t)t * 8;
    #pragma unroll
    for (int j = 0; j < 8; ++j) dst[j] = f2bf(W1[(k0 + j) * HD + col]);
}

// --- GEMM1 (MFMA) + fused att1: h1b[N,64](bf16), als/ald[N,8] --------------
__global__ __launch_bounds__(256) void gemm1att_kernel(const float* __restrict__ x,
                                                       const unsigned short* __restrict__ wf,
                                                       const float* __restrict__ a1s,
                                                       const float* __restrict__ a1d,
                                                       unsigned short* __restrict__ h1b,
                                                       float* __restrict__ als,
                                                       float* __restrict__ ald) {
    __shared__ float ls[64][65];                   // f32 h stage for att halves
    const int wave = threadIdx.x >> 6;
    const int lane = threadIdx.x & 63;
    int arow = blockIdx.x * 64 + wave * 16 + (lane & 15);
    if (arow >= N_NODES) arow = N_NODES - 1;       // clamp for load only
    const float* xp = x + (size_t)arow * F_IN + (lane >> 4) * 8;
    const short8* wp = (const short8*)wf;

    f32x4 acc[4] = {};
    #pragma unroll 4
    for (int kt = 0; kt < NKT; ++kt) {
        f32x4 a0 = *(const f32x4*)(xp + kt * 32);
        f32x4 a1 = *(const f32x4*)(xp + kt * 32 + 4);
        union { short8 s; unsigned short u[8]; } af;
        af.u[0] = f2bf(a0.x); af.u[1] = f2bf(a0.y);
        af.u[2] = f2bf(a0.z); af.u[3] = f2bf(a0.w);
        af.u[4] = f2bf(a1.x); af.u[5] = f2bf(a1.y);
        af.u[6] = f2bf(a1.z); af.u[7] = f2bf(a1.w);
        #pragma unroll
        for (int ct = 0; ct < 4; ++ct) {
            short8 bf = wp[kt * 256 + ct * 64 + lane];
            acc[ct] = __builtin_amdgcn_mfma_f32_16x16x32_bf16(af.s, bf, acc[ct], 0, 0, 0);
        }
    }
    // C/D layout: col = lane&15, row = (lane>>4)*4 + r
    const int lrow_base = wave * 16 + (lane >> 4) * 4;
    const int ocol = lane & 15;
    #pragma unroll
    for (int ct = 0; ct < 4; ++ct) {
        #pragma unroll
        for (int r = 0; r < 4; ++r) {
            int lrow = lrow_base + r;
            int orow = blockIdx.x * 64 + lrow;
            ls[lrow][ct * 16 + ocol] = acc[ct][r];
            if (orow < N_NODES)
                h1b[(size_t)orow * HD + ct * 16 + ocol] = f2bf(acc[ct][r]);
        }
    }
    __syncthreads();
    // attention halves: 512 (row,head) tasks over 256 threads
    #pragma unroll
    for (int task = threadIdx.x; task < 64 * 8; task += 256) {
        int r = task >> 3, h = task & 7;
        int node = blockIdx.x * 64 + r;
        if (node < N_NODES) {
            float s = 0.f, d = 0.f;
            #pragma unroll
            for (int k = 0; k < 8; ++k) {
                float v = ls[r][h * 8 + k];
                s += v * a1s[h * 8 + k];
                d += v * a1d[h * 8 + k];
            }
            als[node * 8 + h] = s;
            ald[node * 8 + h] = d;
        }
    }
}

// --- binscatter into fixed-capacity bucket regions (LDS-aggregated) --------
__global__ __launch_bounds__(256) void binscatter_kernel(const int* __restrict__ ei,
                                                         int* __restrict__ bcur,
                                                         int2* __restrict__ pairs) {
    __shared__ int cnt[NBK];
    __shared__ int bas[NBK];
    const int e0 = blockIdx.x * SCHUNK;
    int e1 = e0 + SCHUNK; if (e1 > N_EDGES) e1 = N_EDGES;
    for (int b = threadIdx.x; b < NBK; b += 256) cnt[b] = 0;
    __syncthreads();
    for (int i = e0 + threadIdx.x; i < e1; i += 256)
        atomicAdd(&cnt[ei[N_EDGES + i] >> 7], 1);
    __syncthreads();
    for (int b = threadIdx.x; b < NBK; b += 256) {
        int c = cnt[b];
        bas[b] = c ? atomicAdd(&bcur[b], c) : 0;
        cnt[b] = 0;                                   // reuse as local cursor
    }
    __syncthreads();
    for (int i = e0 + threadIdx.x; i < e1; i += 256) {
        int s = ei[i];
        int t = ei[N_EDGES + i];
        int b = t >> 7;
        int pos = bas[b] + atomicAdd(&cnt[b], 1);
        if (pos < ECAP) pairs[(size_t)b * ECAP + pos] = make_int2(s, t);
    }
}

// ---- gather layer 1: per-bucket block, LDS counting sort + shfl-dedup p -----
// 512 threads = 8 waves; wave w handles nodes [w*16, w*16+16) of the bucket.
__global__ __launch_bounds__(512) void gather1_kernel(
        const int* __restrict__ bcur, const int2* __restrict__ pairs,
        const float* __restrict__ als, const float* __restrict__ ald,
        const unsigned short* __restrict__ h1b, const float* __restrict__ b1,
        const float* __restrict__ W2, const float* __restrict__ a2s,
        const float* __restrict__ a2d,
        unsigned short* __restrict__ g2b, float* __restrict__ al2s,
        float* __restrict__ al2d) {
    __shared__ int cnt[BS];
    __shared__ int start[BS];
    __shared__ int srcl[ECAP];
    const int tid = threadIdx.x;
    const int wave = tid >> 6, lane = tid & 63, h = lane >> 3;
    const int e8 = lane & 7, base8 = lane & 56;
    const int n0 = blockIdx.x * BS;
    const int2* bp = pairs + (size_t)blockIdx.x * ECAP;
    int ne = bcur[blockIdx.x]; if (ne > ECAP) ne = ECAP;
    if (tid < BS) cnt[tid] = 0;
    __syncthreads();
    // count per node
    for (int k = tid; k < ne; k += 512)
        atomicAdd(&cnt[bp[k].y & (BS - 1)], 1);
    __syncthreads();
    // exclusive scan of 128 counts by wave 0 (two 64-lane scans)
    if (tid < 64) {
        int a = cnt[lane], b = cnt[64 + lane];
        int xx = a;
        #pragma unroll
        for (int o = 1; o < 64; o <<= 1) { int u = __shfl_up(xx, o, 64); if (lane >= o) xx += u; }
        int totalA = __shfl(xx, 63, 64);
        int yy = b;
        #pragma unroll
        for (int o = 1; o < 64; o <<= 1) { int u = __shfl_up(yy, o, 64); if (lane >= o) yy += u; }
        start[lane] = xx - a;
        start[64 + lane] = totalA + yy - b;
        cnt[lane] = 0; cnt[64 + lane] = 0;            // reuse as cursors
    }
    __syncthreads();
    // place src ids per node
    for (int k = tid; k < ne; k += 512) {
        int2 pr = bp[k];
        int ln = pr.y & (BS - 1);
        int pos = start[ln] + atomicAdd(&cnt[ln], 1);
        srcl[pos] = pr.x;
    }
    __syncthreads();

    // per-node gather: 8-edge chunks, 1 exp/lane/chunk, shfl-broadcast p
    float w[CC];
    #pragma unroll
    for (int c = 0; c < CC; ++c) w[c] = W2[lane * CC + c];
    for (int n = wave * 16; n < wave * 16 + 16; ++n) {
        int node = n0 + n;
        if (node >= N_NODES) break;
        const float aldt = ald[node * 8 + h];
        float e = als[node * 8 + h] + aldt;            // self loop
        e = (e >= 0.f) ? e : 0.2f * e;
        float p = __expf(e);
        float acc = p * bf2f(h1b[(size_t)node * HD + lane]);
        float z = p;
        int k = start[n];
        const int ke = k + cnt[n];
        for (; k + 8 <= ke; k += 8) {
            int s_own = srcl[k + e8];
            float ee = als[s_own * 8 + h] + aldt;
            ee = (ee >= 0.f) ? ee : 0.2f * ee;
            float pv = __expf(ee);
            #pragma unroll
            for (int q = 0; q < 8; ++q) {
                int se = srcl[k + q];
                float pe = __shfl(pv, base8 | q, 64);
                float ve = bf2f(h1b[(size_t)se * HD + lane]);
                z += pe;
                acc = fmaf(pe, ve, acc);
            }
        }
        if (k < ke) {                                  // masked final chunk
            const int m = ke - k;
            int idx = k + ((e8 < m) ? e8 : (m - 1));
            int s_own = srcl[idx];
            float ee = als[s_own * 8 + h] + aldt;
            ee = (ee >= 0.f) ? ee : 0.2f * ee;
            float pv = __expf(ee);
            for (int q = 0; q < m; ++q) {
                int se = srcl[k + q];
                float pe = __shfl(pv, base8 | q, 64);
                float ve = bf2f(h1b[(size_t)se * HD + lane]);
                z += pe;
                acc = fmaf(pe, ve, acc);
            }
        }
        // epilogue: alpha-normalize + bias + ELU
        float v = acc / z + b1[lane];
        v = (v > 0.f) ? v : (__expf(v) - 1.f);
        // fused GEMM2: g[c] = sum_j v_j * W2[j][c]  (butterfly over the wave)
        float g[CC];
        #pragma unroll
        for (int c = 0; c < CC; ++c) {
            float r = v * w[c];
            #pragma unroll
            for (int d = 1; d < 64; d <<= 1) r += __shfl_xor(r, d, 64);
            g[c] = r;
        }
        float s2 = 0.f, d2 = 0.f;
        #pragma unroll
        for (int c = 0; c < CC; ++c) { s2 += g[c] * a2s[c]; d2 += g[c] * a2d[c]; }
        if (lane < CC) g2b[(size_t)node * 8 + lane] = f2bf(g[lane]);
        if (lane == CC) g2b[(size_t)node * 8 + CC] = 0;
        if (lane == 8) al2s[node] = s2;
        if (lane == 9) al2d[node] = d2;
    }
}

// ---- gather layer 2: per-bucket block, LDS sort + shfl-dedup p --------------
__global__ __launch_bounds__(256) void gather2_kernel(
        const int* __restrict__ bcur, const int2* __restrict__ pairs,
        const float* __restrict__ al2s, const float* __restrict__ al2d,
        const unsigned short* __restrict__ g2b, const float* __restrict__ b2,
        float* __restrict__ out) {
    __shared__ int cnt[BS];
    __shared__ int start[BS];
    __shared__ int srcl[ECAP];
    const int tid = threadIdx.x;
    const int lane = tid & 63;
    const int grp = tid >> 3, c = tid & 7;         // 32 groups of 8 lanes
    const int base8 = lane & 56;
    const int n0 = blockIdx.x * BS;
    const int2* bp = pairs + (size_t)blockIdx.x * ECAP;
    int ne = bcur[blockIdx.x]; if (ne > ECAP) ne = ECAP;
    if (tid < BS) cnt[tid] = 0;
    __syncthreads();
    for (int k = tid; k < ne; k += 256)
        atomicAdd(&cnt[bp[k].y & (BS - 1)], 1);
    __syncthreads();
    if (tid < 64) {
        int a = cnt[lane], b = cnt[64 + lane];
        int xx = a;
        #pragma unroll
        for (int o = 1; o < 64; o <<= 1) { int u = __shfl_up(xx, o, 64); if (lane >= o) xx += u; }
        int totalA = __shfl(xx, 63, 64);
        int yy = b;
        #pragma unroll
        for (int o = 1; o < 64; o <<= 1) { int u = __shfl_up(yy, o, 64); if (lane >= o) yy += u; }
        start[lane] = xx - a;
        start[64 + lane] = totalA + yy - b;
        cnt[lane] = 0; cnt[64 + lane] = 0;
    }
    __syncthreads();
    for (int k = tid; k < ne; k += 256) {
        int2 pr = bp[k];
        int ln = pr.y & (BS - 1);
        int pos = start[ln] + atomicAdd(&cnt[ln], 1);
        srcl[pos] = pr.x;
    }
    __syncthreads();

    for (int n = (grp & 31) * 4; n < (grp & 31) * 4 + 4; ++n) {
        int node = n0 + n;
        if (node >= N_NODES) break;
        const float adn = al2d[node];
        float e = al2s[node] + adn;                    // self loop
        e = (e >= 0.f) ? e : 0.2f * e;
        float p = __expf(e);
        float acc = p * bf2f(g2b[(size_t)node * 8 + c]);
        float z = p;
        int k = start[n];
        const int ke = k + cnt[n];
        for (; k + 8 <= ke; k += 8) {
            int s_own = srcl[k + c];
            float ee = al2s[s_own] + adn;
            ee = (ee >= 0.f) ? ee : 0.2f * ee;
            float pv = __expf(ee);
            #pragma unroll
            for (int q = 0; q < 8; ++q) {
                int se = srcl[k + q];
                float pe = __shfl(pv, base8 | q, 64);
                float ve = bf2f(g2b[(size_t)se * 8 + c]);
                z += pe;
                acc = fmaf(pe, ve, acc);
            }
        }
        if (k < ke) {
            const int m = ke - k;
            int idx = k + ((c < m) ? c : (m - 1));
            int s_own = srcl[idx];
            float ee = al2s[s_own] + adn;
            ee = (ee >= 0.f) ? ee : 0.2f * ee;
            float pv = __expf(ee);
            for (int q = 0; q < m; ++q) {
                int se = srcl[k + q];
                float pe = __shfl(pv, base8 | q, 64);
                float ve = bf2f(g2b[(size_t)se * 8 + c]);
                z += pe;
                acc = fmaf(pe, ve, acc);
            }
        }
        float o = (c < CC) ? (acc / z + b2[c]) : -1e30f;
        float m2 = o;
        #pragma unroll
        for (int d = 1; d < 8; d <<= 1) m2 = fmaxf(m2, __shfl_xor(m2, d, 8));
        float ex = (c < CC) ? __expf(o - m2) : 0.f;
        float sum = ex;
        #pragma unroll
        for (int d = 1; d < 8; d <<= 1) sum += __shfl_xor(sum, d, 8);
        float lse = m2 + __logf(sum);
        if (c < CC) out[(size_t)node * CC + c] = o - lse;
    }
}

extern "C" void kernel_launch(void* const* d_in, const int* in_sizes, int n_in,
                              void* d_out, int out_size, void* d_ws, size_t ws_size,
                              hipStream_t stream) {
    const float* x   = (const float*)d_in[0];
    const int*   ei  = (const int*)d_in[1];
    const float* W1  = (const float*)d_in[2];
    const float* a1s = (const float*)d_in[3];
    const float* a1d = (const float*)d_in[4];
    const float* b1  = (const float*)d_in[5];
    const float* W2  = (const float*)d_in[6];
    const float* a2s = (const float*)d_in[7];
    const float* a2d = (const float*)d_in[8];
    const float* b2  = (const float*)d_in[9];
    float* out = (float*)d_out;

    // byte-offset workspace allocator (64B aligned)
    char* base = (char*)d_ws;
    size_t off = 0;
    auto alloc = [&](size_t bytes) { char* p = base + off; off = (off + bytes + 63) & ~(size_t)63; return p; };
    unsigned short* h1b = (unsigned short*)alloc((size_t)N_NODES * HD * 2);
    unsigned short* wf  = (unsigned short*)alloc((size_t)NKT * 4 * 64 * 8 * 2);
    float* als  = (float*)alloc((size_t)N_NODES * 8 * 4);
    float* ald  = (float*)alloc((size_t)N_NODES * 8 * 4);
    unsigned short* g2b = (unsigned short*)alloc((size_t)N_NODES * 8 * 2);
    float* al2s = (float*)alloc((size_t)N_NODES * 4);
    float* al2d = (float*)alloc((size_t)N_NODES * 4);
    int* bcur   = (int*)alloc((size_t)NBK * 4);
    int2* pairs = (int2*)alloc((size_t)NBK * ECAP * 8);

    zerob_kernel<<<1, 1024, 0, stream>>>(bcur);
    w1prep_kernel<<<(NKT * 4 * 64 + 255) / 256, 256, 0, stream>>>(W1, wf);
    binscatter_kernel<<<SBLK, 256, 0, stream>>>(ei, bcur, pairs);

    gemm1att_kernel<<<(N_NODES + 63) / 64, 256, 0, stream>>>(
        x, wf, a1s, a1d, h1b, als, ald);

    gather1_kernel<<<NBK, 512, 0, stream>>>(
        bcur, pairs, als, ald, h1b, b1, W2, a2s, a2d, g2b, al2s, al2d);
    gather2_kernel<<<NBK, 256, 0, stream>>>(
        bcur, pairs, al2s, al2d, g2b, b2, out);
}

// Round 14
// 239.858 us; speedup vs baseline: 4.7503x; 1.0094x over previous
//
#include <hip/hip_runtime.h>
#include <math.h>

#define N_NODES 100000
#define N_EDGES 1600000
#define F_IN 512
#define HD 64                    // H*D = 8*8
#define CC 7
#define NKT (F_IN / 32)                // 16 K-steps for MFMA GEMM1
#define BS 64                          // dst nodes per bucket
#define NBK ((N_NODES + BS - 1) / BS)  // 1563 buckets
#define ECAP 2048                      // fixed edge capacity per bucket (mean 1024, +32 sigma)
#define SCHUNK 4096                    // edges per binscatter block
#define SBLK ((N_EDGES + SCHUNK - 1) / SCHUNK)   // 391 blocks

typedef __attribute__((ext_vector_type(8))) short short8;
typedef __attribute__((ext_vector_type(4))) float f32x4;

// float -> bf16 bits, round-to-nearest-even
__device__ inline unsigned short f2bf(float f) {
    union { float f; unsigned u; } v; v.f = f;
    unsigned u = v.u;
    return (unsigned short)((u + 0x7fffu + ((u >> 16) & 1u)) >> 16);
}
__device__ inline float bf2f(unsigned short b) {
    union { unsigned u; float f; } v; v.u = ((unsigned)b) << 16;
    return v.f;
}

// ---------------- zero bucket cursors ----------------
__global__ void zerob_kernel(int* __restrict__ bcur) {
    int i = blockIdx.x * 1024 + threadIdx.x;
    if (i < NBK) bcur[i] = 0;
}

// ---- W1 -> bf16 in exact B-fragment order: wf[kt][ct][lane][8] ----
__global__ void w1prep_kernel(const float* __restrict__ W1,
                              unsigned short* __restrict__ wf) {
    int t = blockIdx.x * 256 + threadIdx.x;       // [0, NKT*4*64)
    if (t >= NKT * 4 * 64) return;
    int lane = t & 63;
    int ct = (t >> 6) & 3;
    int kt = t >> 8;
    int k0 = kt * 32 + (lane >> 4) * 8;
    int col = ct * 16 + (lane & 15);
    unsigned short* dst = wf + (size_t)t * 8;
    #pragma unroll
    for (int j = 0; j < 8; ++j) dst[j] = f2bf(W1[(k0 + j) * HD + col]);
}

// --- GEMM1 (MFMA) + fused att1: h1b[N,64](bf16), als/ald[N,8] --------------
__global__ __launch_bounds__(256) void gemm1att_kernel(const float* __restrict__ x,
                                                       const unsigned short* __restrict__ wf,
                                                       const float* __restrict__ a1s,
                                                       const float* __restrict__ a1d,
                                                       unsigned short* __restrict__ h1b,
                                                       float* __restrict__ als,
                                                       float* __restrict__ ald) {
    __shared__ float ls[64][65];                   // f32 h stage for att halves
    const int wave = threadIdx.x >> 6;
    const int lane = threadIdx.x & 63;
    int arow = blockIdx.x * 64 + wave * 16 + (lane & 15);
    if (arow >= N_NODES) arow = N_NODES - 1;       // clamp for load only
    const float* xp = x + (size_t)arow * F_IN + (lane >> 4) * 8;
    const short8* wp = (const short8*)wf;

    f32x4 acc[4] = {};
    #pragma unroll 4
    for (int kt = 0; kt < NKT; ++kt) {
        f32x4 a0 = *(const f32x4*)(xp + kt * 32);
        f32x4 a1 = *(const f32x4*)(xp + kt * 32 + 4);
        union { short8 s; unsigned short u[8]; } af;
        af.u[0] = f2bf(a0.x); af.u[1] = f2bf(a0.y);
        af.u[2] = f2bf(a0.z); af.u[3] = f2bf(a0.w);
        af.u[4] = f2bf(a1.x); af.u[5] = f2bf(a1.y);
        af.u[6] = f2bf(a1.z); af.u[7] = f2bf(a1.w);
        #pragma unroll
        for (int ct = 0; ct < 4; ++ct) {
            short8 bf = wp[kt * 256 + ct * 64 + lane];
            acc[ct] = __builtin_amdgcn_mfma_f32_16x16x32_bf16(af.s, bf, acc[ct], 0, 0, 0);
        }
    }
    // C/D layout: col = lane&15, row = (lane>>4)*4 + r
    const int lrow_base = wave * 16 + (lane >> 4) * 4;
    const int ocol = lane & 15;
    #pragma unroll
    for (int ct = 0; ct < 4; ++ct) {
        #pragma unroll
        for (int r = 0; r < 4; ++r) {
            int lrow = lrow_base + r;
            int orow = blockIdx.x * 64 + lrow;
            ls[lrow][ct * 16 + ocol] = acc[ct][r];
            if (orow < N_NODES)
                h1b[(size_t)orow * HD + ct * 16 + ocol] = f2bf(acc[ct][r]);
        }
    }
    __syncthreads();
    // attention halves: 512 (row,head) tasks over 256 threads
    #pragma unroll
    for (int task = threadIdx.x; task < 64 * 8; task += 256) {
        int r = task >> 3, h = task & 7;
        int node = blockIdx.x * 64 + r;
        if (node < N_NODES) {
            float s = 0.f, d = 0.f;
            #pragma unroll
            for (int k = 0; k < 8; ++k) {
                float v = ls[r][h * 8 + k];
                s += v * a1s[h * 8 + k];
                d += v * a1d[h * 8 + k];
            }
            als[node * 8 + h] = s;
            ald[node * 8 + h] = d;
        }
    }
}

// --- binscatter into fixed-capacity bucket regions (LDS-aggregated) --------
__global__ __launch_bounds__(256) void binscatter_kernel(const int* __restrict__ ei,
                                                         int* __restrict__ bcur,
                                                         int2* __restrict__ pairs) {
    __shared__ int cnt[NBK];
    __shared__ int bas[NBK];
    const int e0 = blockIdx.x * SCHUNK;
    int e1 = e0 + SCHUNK; if (e1 > N_EDGES) e1 = N_EDGES;
    for (int b = threadIdx.x; b < NBK; b += 256) cnt[b] = 0;
    __syncthreads();
    for (int i = e0 + threadIdx.x; i < e1; i += 256)
        atomicAdd(&cnt[ei[N_EDGES + i] >> 6], 1);
    __syncthreads();
    for (int b = threadIdx.x; b < NBK; b += 256) {
        int c = cnt[b];
        bas[b] = c ? atomicAdd(&bcur[b], c) : 0;
        cnt[b] = 0;                                   // reuse as local cursor
    }
    __syncthreads();
    for (int i = e0 + threadIdx.x; i < e1; i += 256) {
        int s = ei[i];
        int t = ei[N_EDGES + i];
        int b = t >> 6;
        int pos = bas[b] + atomicAdd(&cnt[b], 1);
        if (pos < ECAP) pairs[(size_t)b * ECAP + pos] = make_int2(s, t);
    }
}

// ---- gather layer 1: per-bucket block, LDS counting sort + shfl-dedup p -----
// 256 threads = 4 waves; wave w handles nodes [w*16, w*16+16) of the bucket.
__global__ __launch_bounds__(256) void gather1_kernel(
        const int* __restrict__ bcur, const int2* __restrict__ pairs,
        const float* __restrict__ als, const float* __restrict__ ald,
        const unsigned short* __restrict__ h1b, const float* __restrict__ b1,
        const float* __restrict__ W2, const float* __restrict__ a2s,
        const float* __restrict__ a2d,
        unsigned short* __restrict__ g2b, float* __restrict__ al2s,
        float* __restrict__ al2d) {
    __shared__ int cnt[BS];
    __shared__ int start[BS];
    __shared__ int srcl[ECAP];
    const int tid = threadIdx.x;
    const int wave = tid >> 6, lane = tid & 63, h = lane >> 3;
    const int e8 = lane & 7, base8 = lane & 56;
    const int n0 = blockIdx.x * BS;
    const int2* bp = pairs + (size_t)blockIdx.x * ECAP;
    int ne = bcur[blockIdx.x]; if (ne > ECAP) ne = ECAP;
    if (tid < BS) cnt[tid] = 0;
    __syncthreads();
    // count per node
    for (int k = tid; k < ne; k += 256)
        atomicAdd(&cnt[bp[k].y & (BS - 1)], 1);
    __syncthreads();
    // exclusive scan of 64 counts by wave 0
    if (tid < 64) {
        int a = cnt[lane];
        int xx = a;
        #pragma unroll
        for (int o = 1; o < 64; o <<= 1) { int u = __shfl_up(xx, o, 64); if (lane >= o) xx += u; }
        start[lane] = xx - a;
        cnt[lane] = 0;                                // reuse as cursor
    }
    __syncthreads();
    // place src ids per node
    for (int k = tid; k < ne; k += 256) {
        int2 pr = bp[k];
        int ln = pr.y & (BS - 1);
        int pos = start[ln] + atomicAdd(&cnt[ln], 1);
        srcl[pos] = pr.x;
    }
    __syncthreads();

    // per-node gather: 8-edge chunks, 1 exp/lane/chunk, shfl-broadcast p
    float w[CC];
    #pragma unroll
    for (int c = 0; c < CC; ++c) w[c] = W2[lane * CC + c];
    for (int n = wave * 16; n < wave * 16 + 16; ++n) {
        int node = n0 + n;
        if (node >= N_NODES) break;
        const float aldt = ald[node * 8 + h];
        float e = als[node * 8 + h] + aldt;            // self loop
        e = (e >= 0.f) ? e : 0.2f * e;
        float p = __expf(e);
        float acc = p * bf2f(h1b[(size_t)node * HD + lane]);
        float z = p;
        int k = start[n];
        const int ke = k + cnt[n];
        for (; k + 8 <= ke; k += 8) {
            int s_own = srcl[k + e8];
            float ee = als[s_own * 8 + h] + aldt;
            ee = (ee >= 0.f) ? ee : 0.2f * ee;
            float pv = __expf(ee);
            #pragma unroll
            for (int q = 0; q < 8; ++q) {
                int se = srcl[k + q];
                float pe = __shfl(pv, base8 | q, 64);
                float ve = bf2f(h1b[(size_t)se * HD + lane]);
                z += pe;
                acc = fmaf(pe, ve, acc);
            }
        }
        if (k < ke) {                                  // masked final chunk
            const int m = ke - k;
            int idx = k + ((e8 < m) ? e8 : (m - 1));
            int s_own = srcl[idx];
            float ee = als[s_own * 8 + h] + aldt;
            ee = (ee >= 0.f) ? ee : 0.2f * ee;
            float pv = __expf(ee);
            for (int q = 0; q < m; ++q) {
                int se = srcl[k + q];
                float pe = __shfl(pv, base8 | q, 64);
                float ve = bf2f(h1b[(size_t)se * HD + lane]);
                z += pe;
                acc = fmaf(pe, ve, acc);
            }
        }
        // epilogue: alpha-normalize + bias + ELU
        float v = acc / z + b1[lane];
        v = (v > 0.f) ? v : (__expf(v) - 1.f);
        // fused GEMM2: g[c] = sum_j v_j * W2[j][c]  (butterfly over the wave)
        float g[CC];
        #pragma unroll
        for (int c = 0; c < CC; ++c) {
            float r = v * w[c];
            #pragma unroll
            for (int d = 1; d < 64; d <<= 1) r += __shfl_xor(r, d, 64);
            g[c] = r;
        }
        float s2 = 0.f, d2 = 0.f;
        #pragma unroll
        for (int c = 0; c < CC; ++c) { s2 += g[c] * a2s[c]; d2 += g[c] * a2d[c]; }
        if (lane < CC) g2b[(size_t)node * 8 + lane] = f2bf(g[lane]);
        if (lane == CC) g2b[(size_t)node * 8 + CC] = 0;
        if (lane == 8) al2s[node] = s2;
        if (lane == 9) al2d[node] = d2;
    }
}

// ---- gather layer 2: per-bucket block, LDS sort + shfl-dedup p --------------
__global__ __launch_bounds__(256) void gather2_kernel(
        const int* __restrict__ bcur, const int2* __restrict__ pairs,
        const float* __restrict__ al2s, const float* __restrict__ al2d,
        const unsigned short* __restrict__ g2b, const float* __restrict__ b2,
        float* __restrict__ out) {
    __shared__ int cnt[BS];
    __shared__ int start[BS];
    __shared__ int srcl[ECAP];
    const int tid = threadIdx.x;
    const int lane = tid & 63;
    const int grp = tid >> 3, c = tid & 7;         // 32 groups of 8 lanes
    const int base8 = lane & 56;
    const int n0 = blockIdx.x * BS;
    const int2* bp = pairs + (size_t)blockIdx.x * ECAP;
    int ne = bcur[blockIdx.x]; if (ne > ECAP) ne = ECAP;
    if (tid < BS) cnt[tid] = 0;
    __syncthreads();
    for (int k = tid; k < ne; k += 256)
        atomicAdd(&cnt[bp[k].y & (BS - 1)], 1);
    __syncthreads();
    if (tid < 64) {
        int a = cnt[lane];
        int xx = a;
        #pragma unroll
        for (int o = 1; o < 64; o <<= 1) { int u = __shfl_up(xx, o, 64); if (lane >= o) xx += u; }
        start[lane] = xx - a;
        cnt[lane] = 0;
    }
    __syncthreads();
    for (int k = tid; k < ne; k += 256) {
        int2 pr = bp[k];
        int ln = pr.y & (BS - 1);
        int pos = start[ln] + atomicAdd(&cnt[ln], 1);
        srcl[pos] = pr.x;
    }
    __syncthreads();

    for (int n = grp * 2; n < grp * 2 + 2; ++n) {
        int node = n0 + n;
        if (node >= N_NODES) break;
        const float adn = al2d[node];
        float e = al2s[node] + adn;                    // self loop
        e = (e >= 0.f) ? e : 0.2f * e;
        float p = __expf(e);
        float acc = p * bf2f(g2b[(size_t)node * 8 + c]);
        float z = p;
        int k = start[n];
        const int ke = k + cnt[n];
        for (; k + 8 <= ke; k += 8) {
            int s_own = srcl[k + c];
            float ee = al2s[s_own] + adn;
            ee = (ee >= 0.f) ? ee : 0.2f * ee;
            float pv = __expf(ee);
            #pragma unroll
            for (int q = 0; q < 8; ++q) {
                int se = srcl[k + q];
                float pe = __shfl(pv, base8 | q, 64);
                float ve = bf2f(g2b[(size_t)se * 8 + c]);
                z += pe;
                acc = fmaf(pe, ve, acc);
            }
        }
        if (k < ke) {
            const int m = ke - k;
            int idx = k + ((c < m) ? c : (m - 1));
            int s_own = srcl[idx];
            float ee = al2s[s_own] + adn;
            ee = (ee >= 0.f) ? ee : 0.2f * ee;
            float pv = __expf(ee);
            for (int q = 0; q < m; ++q) {
                int se = srcl[k + q];
                float pe = __shfl(pv, base8 | q, 64);
                float ve = bf2f(g2b[(size_t)se * 8 + c]);
                z += pe;
                acc = fmaf(pe, ve, acc);
            }
        }
        float o = (c < CC) ? (acc / z + b2[c]) : -1e30f;
        float m2 = o;
        #pragma unroll
        for (int d = 1; d < 8; d <<= 1) m2 = fmaxf(m2, __shfl_xor(m2, d, 8));
        float ex = (c < CC) ? __expf(o - m2) : 0.f;
        float sum = ex;
        #pragma unroll
        for (int d = 1; d < 8; d <<= 1) sum += __shfl_xor(sum, d, 8);
        float lse = m2 + __logf(sum);
        if (c < CC) out[(size_t)node * CC + c] = o - lse;
    }
}

extern "C" void kernel_launch(void* const* d_in, const int* in_sizes, int n_in,
                              void* d_out, int out_size, void* d_ws, size_t ws_size,
                              hipStream_t stream) {
    const float* x   = (const float*)d_in[0];
    const int*   ei  = (const int*)d_in[1];
    const float* W1  = (const float*)d_in[2];
    const float* a1s = (const float*)d_in[3];
    const float* a1d = (const float*)d_in[4];
    const float* b1  = (const float*)d_in[5];
    const float* W2  = (const float*)d_in[6];
    const float* a2s = (const float*)d_in[7];
    const float* a2d = (const float*)d_in[8];
    const float* b2  = (const float*)d_in[9];
    float* out = (float*)d_out;

    // byte-offset workspace allocator (64B aligned)
    char* base = (char*)d_ws;
    size_t off = 0;
    auto alloc = [&](size_t bytes) { char* p = base + off; off = (off + bytes + 63) & ~(size_t)63; return p; };
    unsigned short* h1b = (unsigned short*)alloc((size_t)N_NODES * HD * 2);
    unsigned short* wf  = (unsigned short*)alloc((size_t)NKT * 4 * 64 * 8 * 2);
    float* als  = (float*)alloc((size_t)N_NODES * 8 * 4);
    float* ald  = (float*)alloc((size_t)N_NODES * 8 * 4);
    unsigned short* g2b = (unsigned short*)alloc((size_t)N_NODES * 8 * 2);
    float* al2s = (float*)alloc((size_t)N_NODES * 4);
    float* al2d = (float*)alloc((size_t)N_NODES * 4);
    int* bcur   = (int*)alloc((size_t)NBK * 4);
    int2* pairs = (int2*)alloc((size_t)NBK * ECAP * 8);

    zerob_kernel<<<(NBK + 1023) / 1024, 1024, 0, stream>>>(bcur);
    w1prep_kernel<<<(NKT * 4 * 64 + 255) / 256, 256, 0, stream>>>(W1, wf);
    binscatter_kernel<<<SBLK, 256, 0, stream>>>(ei, bcur, pairs);

    gemm1att_kernel<<<(N_NODES + 63) / 64, 256, 0, stream>>>(
        x, wf, a1s, a1d, h1b, als, ald);

    gather1_kernel<<<NBK, 256, 0, stream>>>(
        bcur, pairs, als, ald, h1b, b1, W2, a2s, a2d, g2b, al2s, al2d);
    gather2_kernel<<<NBK, 256, 0, stream>>>(
        bcur, pairs, al2s, al2d, g2b, b2, out);
}

// Round 15
// 223.452 us; speedup vs baseline: 5.0991x; 1.0734x over previous
//
#include <hip/hip_runtime.h>
#include <math.h>

#define N_NODES 100000
#define N_EDGES 1600000
#define F_IN 512
#define HD 64                    // H*D = 8*8
#define CC 7
#define NKT (F_IN / 32)                // 16 K-steps for MFMA GEMM1
#define BS 64                          // dst nodes per bucket
#define NBK ((N_NODES + BS - 1) / BS)  // 1563 buckets
#define ECAP 2048                      // fixed edge capacity per bucket (mean 1024)
#define SCHUNK 4096                    // edges per binscatter block
#define SBLK ((N_EDGES + SCHUNK - 1) / SCHUNK)   // 391 blocks

typedef __attribute__((ext_vector_type(8))) short short8;
typedef __attribute__((ext_vector_type(4))) float f32x4;

// float -> bf16 bits, round-to-nearest-even
__device__ inline unsigned short f2bf(float f) {
    union { float f; unsigned u; } v; v.f = f;
    unsigned u = v.u;
    return (unsigned short)((u + 0x7fffu + ((u >> 16) & 1u)) >> 16);
}
__device__ inline float bf2f(unsigned short b) {
    union { unsigned u; float f; } v; v.u = ((unsigned)b) << 16;
    return v.f;
}

// ---------------- zero bucket cursors ----------------
__global__ void zerob_kernel(int* __restrict__ bcur) {
    int i = blockIdx.x * 1024 + threadIdx.x;
    if (i < NBK) bcur[i] = 0;
}

// ---- W1 -> bf16 in exact B-fragment order: wf[kt][ct][lane][8] ----
__global__ void w1prep_kernel(const float* __restrict__ W1,
                              unsigned short* __restrict__ wf) {
    int t = blockIdx.x * 256 + threadIdx.x;       // [0, NKT*4*64)
    if (t >= NKT * 4 * 64) return;
    int lane = t & 63;
    int ct = (t >> 6) & 3;
    int kt = t >> 8;
    int k0 = kt * 32 + (lane >> 4) * 8;
    int col = ct * 16 + (lane & 15);
    unsigned short* dst = wf + (size_t)t * 8;
    #pragma unroll
    for (int j = 0; j < 8; ++j) dst[j] = f2bf(W1[(k0 + j) * HD + col]);
}

// --- GEMM1 (MFMA) + fused att1: h1b[N,64](bf16), als/ald[N,8] --------------
__global__ __launch_bounds__(256) void gemm1att_kernel(const float* __restrict__ x,
                                                       const unsigned short* __restrict__ wf,
                                                       const float* __restrict__ a1s,
                                                       const float* __restrict__ a1d,
                                                       unsigned short* __restrict__ h1b,
                                                       float* __restrict__ als,
                                                       float* __restrict__ ald) {
    __shared__ float ls[64][65];                   // f32 h stage for att halves
    const int wave = threadIdx.x >> 6;
    const int lane = threadIdx.x & 63;
    int arow = blockIdx.x * 64 + wave * 16 + (lane & 15);
    if (arow >= N_NODES) arow = N_NODES - 1;       // clamp for load only
    const float* xp = x + (size_t)arow * F_IN + (lane >> 4) * 8;
    const short8* wp = (const short8*)wf;

    f32x4 acc[4] = {};
    #pragma unroll 4
    for (int kt = 0; kt < NKT; ++kt) {
        f32x4 a0 = *(const f32x4*)(xp + kt * 32);
        f32x4 a1 = *(const f32x4*)(xp + kt * 32 + 4);
        union { short8 s; unsigned short u[8]; } af;
        af.u[0] = f2bf(a0.x); af.u[1] = f2bf(a0.y);
        af.u[2] = f2bf(a0.z); af.u[3] = f2bf(a0.w);
        af.u[4] = f2bf(a1.x); af.u[5] = f2bf(a1.y);
        af.u[6] = f2bf(a1.z); af.u[7] = f2bf(a1.w);
        #pragma unroll
        for (int ct = 0; ct < 4; ++ct) {
            short8 bf = wp[kt * 256 + ct * 64 + lane];
            acc[ct] = __builtin_amdgcn_mfma_f32_16x16x32_bf16(af.s, bf, acc[ct], 0, 0, 0);
        }
    }
    // C/D layout: col = lane&15, row = (lane>>4)*4 + r
    const int lrow_base = wave * 16 + (lane >> 4) * 4;
    const int ocol = lane & 15;
    #pragma unroll
    for (int ct = 0; ct < 4; ++ct) {
        #pragma unroll
        for (int r = 0; r < 4; ++r) {
            int lrow = lrow_base + r;
            int orow = blockIdx.x * 64 + lrow;
            ls[lrow][ct * 16 + ocol] = acc[ct][r];
            if (orow < N_NODES)
                h1b[(size_t)orow * HD + ct * 16 + ocol] = f2bf(acc[ct][r]);
        }
    }
    __syncthreads();
    // attention halves: 512 (row,head) tasks over 256 threads
    #pragma unroll
    for (int task = threadIdx.x; task < 64 * 8; task += 256) {
        int r = task >> 3, h = task & 7;
        int node = blockIdx.x * 64 + r;
        if (node < N_NODES) {
            float s = 0.f, d = 0.f;
            #pragma unroll
            for (int k = 0; k < 8; ++k) {
                float v = ls[r][h * 8 + k];
                s += v * a1s[h * 8 + k];
                d += v * a1d[h * 8 + k];
            }
            als[node * 8 + h] = s;
            ald[node * 8 + h] = d;
        }
    }
}

// --- binscatter into fixed-capacity bucket regions (LDS-aggregated) --------
__global__ __launch_bounds__(256) void binscatter_kernel(const int* __restrict__ ei,
                                                         int* __restrict__ bcur,
                                                         int2* __restrict__ pairs) {
    __shared__ int cnt[NBK];
    __shared__ int bas[NBK];
    const int e0 = blockIdx.x * SCHUNK;
    int e1 = e0 + SCHUNK; if (e1 > N_EDGES) e1 = N_EDGES;
    for (int b = threadIdx.x; b < NBK; b += 256) cnt[b] = 0;
    __syncthreads();
    for (int i = e0 + threadIdx.x; i < e1; i += 256)
        atomicAdd(&cnt[ei[N_EDGES + i] >> 6], 1);
    __syncthreads();
    for (int b = threadIdx.x; b < NBK; b += 256) {
        int c = cnt[b];
        bas[b] = c ? atomicAdd(&bcur[b], c) : 0;
        cnt[b] = 0;                                   // reuse as local cursor
    }
    __syncthreads();
    for (int i = e0 + threadIdx.x; i < e1; i += 256) {
        int s = ei[i];
        int t = ei[N_EDGES + i];
        int b = t >> 6;
        int pos = bas[b] + atomicAdd(&cnt[b], 1);
        if (pos < ECAP) pairs[(size_t)b * ECAP + pos] = make_int2(s, t);
    }
}

// --- sortcsr: per-bucket LDS counting sort -> csr_src, rowptr, rowcnt -------
__global__ __launch_bounds__(256) void sortcsr_kernel(const int* __restrict__ bcur,
                                                      const int2* __restrict__ pairs,
                                                      int* __restrict__ csr_src,
                                                      int* __restrict__ rowptr,
                                                      int* __restrict__ rowcnt) {
    __shared__ int cnt[BS];
    __shared__ int start[BS];
    __shared__ int srcl[ECAP];
    const int tid = threadIdx.x;
    const int lane = tid & 63;
    const int n0 = blockIdx.x * BS;
    const size_t bbase = (size_t)blockIdx.x * ECAP;
    const int2* bp = pairs + bbase;
    int ne = bcur[blockIdx.x]; if (ne > ECAP) ne = ECAP;
    if (tid < BS) cnt[tid] = 0;
    __syncthreads();
    for (int k = tid; k < ne; k += 256)
        atomicAdd(&cnt[bp[k].y & (BS - 1)], 1);
    __syncthreads();
    if (tid < 64) {
        int a = cnt[lane];
        int xx = a;
        #pragma unroll
        for (int o = 1; o < 64; o <<= 1) { int u = __shfl_up(xx, o, 64); if (lane >= o) xx += u; }
        start[lane] = xx - a;
        cnt[lane] = 0;                                // reuse as cursor
    }
    __syncthreads();
    for (int k = tid; k < ne; k += 256) {
        int2 pr = bp[k];
        int ln = pr.y & (BS - 1);
        int pos = start[ln] + atomicAdd(&cnt[ln], 1);
        srcl[pos] = pr.x;
    }
    __syncthreads();
    // coalesced writeback + per-node metadata
    for (int k = tid; k < ne; k += 256) csr_src[bbase + k] = srcl[k];
    if (tid < BS) {
        int node = n0 + tid;
        if (node < N_NODES) {
            rowptr[node] = (int)bbase + start[tid];
            rowcnt[node] = cnt[tid];
        }
    }
}

// ---- gather layer 1: flat per-node wave, shfl-dedup p, batched loads --------
__global__ __launch_bounds__(256) void gather1_kernel(
        const int* __restrict__ rowptr, const int* __restrict__ rowcnt,
        const int* __restrict__ csr_src,
        const float* __restrict__ als, const float* __restrict__ ald,
        const unsigned short* __restrict__ h1b, const float* __restrict__ b1,
        const float* __restrict__ W2, const float* __restrict__ a2s,
        const float* __restrict__ a2d,
        unsigned short* __restrict__ g2b, float* __restrict__ al2s,
        float* __restrict__ al2d) {
    int node = (blockIdx.x * 256 + threadIdx.x) >> 6;    // one wave per node
    if (node >= N_NODES) return;
    const int lane = threadIdx.x & 63;
    const int h = lane >> 3;
    const int e8 = lane & 7, base8 = lane & 56;
    const int rs = rowptr[node], ncnt = rowcnt[node];
    const float aldt = ald[node * 8 + h];
    float e = als[node * 8 + h] + aldt;                  // self loop
    e = (e >= 0.f) ? e : 0.2f * e;
    float p = __expf(e);
    float acc = p * bf2f(h1b[(size_t)node * HD + lane]);
    float z = p;
    int k = 0;
    for (; k + 8 <= ncnt; k += 8) {
        int s_own = csr_src[rs + k + e8];                // coalesced 32B/group
        int se[8];
        #pragma unroll
        for (int q = 0; q < 8; ++q) se[q] = __shfl(s_own, base8 | q, 64);
        float ve[8];
        #pragma unroll
        for (int q = 0; q < 8; ++q) ve[q] = bf2f(h1b[(size_t)se[q] * HD + lane]);
        float ee = als[s_own * 8 + h] + aldt;
        ee = (ee >= 0.f) ? ee : 0.2f * ee;
        float pv = __expf(ee);
        #pragma unroll
        for (int q = 0; q < 8; ++q) {
            float pe = __shfl(pv, base8 | q, 64);
            z += pe;
            acc = fmaf(pe, ve[q], acc);
        }
    }
    if (k < ncnt) {                                      // masked final chunk
        const int m = ncnt - k;
        int idx = rs + k + ((e8 < m) ? e8 : (m - 1));
        int s_own = csr_src[idx];
        int se[8];
        #pragma unroll
        for (int q = 0; q < 8; ++q) se[q] = __shfl(s_own, base8 | q, 64);
        float ee = als[s_own * 8 + h] + aldt;
        ee = (ee >= 0.f) ? ee : 0.2f * ee;
        float pv = __expf(ee);
        for (int q = 0; q < m; ++q) {
            float pe = __shfl(pv, base8 | q, 64);
            float ve = bf2f(h1b[(size_t)se[q] * HD + lane]);
            z += pe;
            acc = fmaf(pe, ve, acc);
        }
    }
    // epilogue: alpha-normalize + bias + ELU
    float v = acc / z + b1[lane];
    v = (v > 0.f) ? v : (__expf(v) - 1.f);
    // fused GEMM2: g[c] = sum_j v_j * W2[j][c]  (butterfly over the wave)
    float w[CC];
    #pragma unroll
    for (int c = 0; c < CC; ++c) w[c] = W2[lane * CC + c];
    float g[CC];
    #pragma unroll
    for (int c = 0; c < CC; ++c) {
        float r = v * w[c];
        #pragma unroll
        for (int d = 1; d < 64; d <<= 1) r += __shfl_xor(r, d, 64);
        g[c] = r;
    }
    float s2 = 0.f, d2 = 0.f;
    #pragma unroll
    for (int c = 0; c < CC; ++c) { s2 += g[c] * a2s[c]; d2 += g[c] * a2d[c]; }
    if (lane < CC) g2b[(size_t)node * 8 + lane] = f2bf(g[lane]);
    if (lane == CC) g2b[(size_t)node * 8 + CC] = 0;
    if (lane == 8) al2s[node] = s2;
    if (lane == 9) al2d[node] = d2;
}

// ---- gather layer 2: flat 8-lane groups, shfl-dedup p, log_softmax ----------
__global__ __launch_bounds__(256) void gather2_kernel(
        const int* __restrict__ rowptr, const int* __restrict__ rowcnt,
        const int* __restrict__ csr_src,
        const float* __restrict__ al2s, const float* __restrict__ al2d,
        const unsigned short* __restrict__ g2b, const float* __restrict__ b2,
        float* __restrict__ out) {
    int gid = blockIdx.x * 256 + threadIdx.x;
    int n = gid >> 3, c = gid & 7;
    if (n >= N_NODES) return;
    const int lane = threadIdx.x & 63;
    const int base8 = lane & 56;
    const int rs = rowptr[n], ncnt = rowcnt[n];
    const float adn = al2d[n];
    float e = al2s[n] + adn;                             // self loop
    e = (e >= 0.f) ? e : 0.2f * e;
    float p = __expf(e);
    float acc = p * bf2f(g2b[(size_t)n * 8 + c]);
    float z = p;
    int k = 0;
    for (; k + 8 <= ncnt; k += 8) {
        int s_own = csr_src[rs + k + c];
        int se[8];
        #pragma unroll
        for (int q = 0; q < 8; ++q) se[q] = __shfl(s_own, base8 | q, 64);
        float ve[8];
        #pragma unroll
        for (int q = 0; q < 8; ++q) ve[q] = bf2f(g2b[(size_t)se[q] * 8 + c]);
        float ee = al2s[s_own] + adn;
        ee = (ee >= 0.f) ? ee : 0.2f * ee;
        float pv = __expf(ee);
        #pragma unroll
        for (int q = 0; q < 8; ++q) {
            float pe = __shfl(pv, base8 | q, 64);
            z += pe;
            acc = fmaf(pe, ve[q], acc);
        }
    }
    if (k < ncnt) {
        const int m = ncnt - k;
        int idx = rs + k + ((c < m) ? c : (m - 1));
        int s_own = csr_src[idx];
        int se[8];
        #pragma unroll
        for (int q = 0; q < 8; ++q) se[q] = __shfl(s_own, base8 | q, 64);
        float ee = al2s[s_own] + adn;
        ee = (ee >= 0.f) ? ee : 0.2f * ee;
        float pv = __expf(ee);
        for (int q = 0; q < m; ++q) {
            float pe = __shfl(pv, base8 | q, 64);
            float ve = bf2f(g2b[(size_t)se[q] * 8 + c]);
            z += pe;
            acc = fmaf(pe, ve, acc);
        }
    }
    float o = (c < CC) ? (acc / z + b2[c]) : -1e30f;
    float m2 = o;
    #pragma unroll
    for (int d = 1; d < 8; d <<= 1) m2 = fmaxf(m2, __shfl_xor(m2, d, 8));
    float ex = (c < CC) ? __expf(o - m2) : 0.f;
    float sum = ex;
    #pragma unroll
    for (int d = 1; d < 8; d <<= 1) sum += __shfl_xor(sum, d, 8);
    float lse = m2 + __logf(sum);
    if (c < CC) out[(size_t)n * CC + c] = o - lse;
}

extern "C" void kernel_launch(void* const* d_in, const int* in_sizes, int n_in,
                              void* d_out, int out_size, void* d_ws, size_t ws_size,
                              hipStream_t stream) {
    const float* x   = (const float*)d_in[0];
    const int*   ei  = (const int*)d_in[1];
    const float* W1  = (const float*)d_in[2];
    const float* a1s = (const float*)d_in[3];
    const float* a1d = (const float*)d_in[4];
    const float* b1  = (const float*)d_in[5];
    const float* W2  = (const float*)d_in[6];
    const float* a2s = (const float*)d_in[7];
    const float* a2d = (const float*)d_in[8];
    const float* b2  = (const float*)d_in[9];
    float* out = (float*)d_out;

    // byte-offset workspace allocator (64B aligned)
    char* base = (char*)d_ws;
    size_t off = 0;
    auto alloc = [&](size_t bytes) { char* p = base + off; off = (off + bytes + 63) & ~(size_t)63; return p; };
    unsigned short* h1b = (unsigned short*)alloc((size_t)N_NODES * HD * 2);
    unsigned short* wf  = (unsigned short*)alloc((size_t)NKT * 4 * 64 * 8 * 2);
    float* als  = (float*)alloc((size_t)N_NODES * 8 * 4);
    float* ald  = (float*)alloc((size_t)N_NODES * 8 * 4);
    unsigned short* g2b = (unsigned short*)alloc((size_t)N_NODES * 8 * 2);
    float* al2s = (float*)alloc((size_t)N_NODES * 4);
    float* al2d = (float*)alloc((size_t)N_NODES * 4);
    int* bcur   = (int*)alloc((size_t)NBK * 4);
    int* rowptr = (int*)alloc((size_t)N_NODES * 4);
    int* rowcnt = (int*)alloc((size_t)N_NODES * 4);
    int* csr_src= (int*)alloc((size_t)NBK * ECAP * 4);
    int2* pairs = (int2*)alloc((size_t)NBK * ECAP * 8);

    zerob_kernel<<<(NBK + 1023) / 1024, 1024, 0, stream>>>(bcur);
    w1prep_kernel<<<(NKT * 4 * 64 + 255) / 256, 256, 0, stream>>>(W1, wf);
    binscatter_kernel<<<SBLK, 256, 0, stream>>>(ei, bcur, pairs);
    sortcsr_kernel<<<NBK, 256, 0, stream>>>(bcur, pairs, csr_src, rowptr, rowcnt);

    gemm1att_kernel<<<(N_NODES + 63) / 64, 256, 0, stream>>>(
        x, wf, a1s, a1d, h1b, als, ald);

    gather1_kernel<<<(N_NODES * 64 + 255) / 256, 256, 0, stream>>>(
        rowptr, rowcnt, csr_src, als, ald, h1b, b1, W2, a2s, a2d, g2b, al2s, al2d);
    gather2_kernel<<<(N_NODES * 8 + 255) / 256, 256, 0, stream>>>(
        rowptr, rowcnt, csr_src, al2s, al2d, g2b, b2, out);
}

// Round 16
// 200.462 us; speedup vs baseline: 5.6838x; 1.1147x over previous
//
#include <hip/hip_runtime.h>
#include <math.h>

#define N_NODES 100000
#define N_EDGES 1600000
#define F_IN 512
#define HD 64                    // H*D = 8*8
#define CC 7
#define NKT (F_IN / 32)                // 16 K-steps for MFMA GEMM1
#define BS 64                          // dst nodes per bucket
#define NBK ((N_NODES + BS - 1) / BS)  // 1563 buckets
#define ECAP 2048                      // fixed edge capacity per bucket (mean 1024, +32 sigma)
#define SCHUNK 4096                    // edges per binscatter block
#define SBLK ((N_EDGES + SCHUNK - 1) / SCHUNK)   // 391 binscatter blocks
#define GEMMBLKS ((N_NODES + 63) / 64)           // 1563 gemm blocks
#define W1WORK (NKT * 4 * 64)                    // 4096 w1prep items

typedef __attribute__((ext_vector_type(8))) short short8;
typedef __attribute__((ext_vector_type(4))) float f32x4;

// float -> bf16 bits, round-to-nearest-even
__device__ inline unsigned short f2bf(float f) {
    union { float f; unsigned u; } v; v.f = f;
    unsigned u = v.u;
    return (unsigned short)((u + 0x7fffu + ((u >> 16) & 1u)) >> 16);
}
__device__ inline float bf2f(unsigned short b) {
    union { unsigned u; float f; } v; v.u = ((unsigned)b) << 16;
    return v.f;
}

// ---- prep: blocks 0..15 convert W1 to B-fragment order; block 16 zeros bcur ----
__global__ __launch_bounds__(256) void prep_kernel(const float* __restrict__ W1,
                                                   unsigned short* __restrict__ wf,
                                                   int* __restrict__ bcur) {
    if (blockIdx.x == 16) {
        for (int i = threadIdx.x; i < NBK; i += 256) bcur[i] = 0;
        return;
    }
    int t = blockIdx.x * 256 + threadIdx.x;       // [0, W1WORK)
    if (t >= W1WORK) return;
    int lane = t & 63;
    int ct = (t >> 6) & 3;
    int kt = t >> 8;
    int k0 = kt * 32 + (lane >> 4) * 8;
    int col = ct * 16 + (lane & 15);
    unsigned short* dst = wf + (size_t)t * 8;
    #pragma unroll
    for (int j = 0; j < 8; ++j) dst[j] = f2bf(W1[(k0 + j) * HD + col]);
}

// --- fused: blocks [0,SBLK) = binscatter; blocks [SBLK, SBLK+GEMMBLKS) = GEMM1+att1 ---
// independent inputs (ei vs x/W1) -> true overlap of latency-bound binning
// under the BW-bound MFMA GEMM.
__global__ __launch_bounds__(256) void fused_kernel(
        const int* __restrict__ ei, int* __restrict__ bcur, int* __restrict__ pairs,
        const float* __restrict__ x, const unsigned short* __restrict__ wf,
        const float* __restrict__ a1s, const float* __restrict__ a1d,
        unsigned short* __restrict__ h1b, float* __restrict__ als,
        float* __restrict__ ald) {
    __shared__ float ls[64 * 65];                  // 16.64 KB; reused as ints by binscatter
    const int bid = blockIdx.x;
    const int tid = threadIdx.x;
    if (bid < SBLK) {
        // ---------------- binscatter (packed 4B pairs) ----------------
        int* cnt = (int*)ls;                       // [NBK]
        int* bas = cnt + NBK;                      // [NBK]  (2*6.25 KB < 16.64 KB)
        const int e0 = bid * SCHUNK;
        int e1 = e0 + SCHUNK; if (e1 > N_EDGES) e1 = N_EDGES;
        for (int b = tid; b < NBK; b += 256) cnt[b] = 0;
        __syncthreads();
        for (int i = e0 + tid; i < e1; i += 256)
            atomicAdd(&cnt[ei[N_EDGES + i] >> 6], 1);
        __syncthreads();
        for (int b = tid; b < NBK; b += 256) {
            int c = cnt[b];
            bas[b] = c ? atomicAdd(&bcur[b], c) : 0;
            cnt[b] = 0;                            // reuse as local cursor
        }
        __syncthreads();
        for (int i = e0 + tid; i < e1; i += 256) {
            int s = ei[i];
            int t = ei[N_EDGES + i];
            int b = t >> 6;
            int pos = bas[b] + atomicAdd(&cnt[b], 1);
            if (pos < ECAP) pairs[(size_t)b * ECAP + pos] = (s << 6) | (t & (BS - 1));
        }
        return;
    }
    // ---------------- GEMM1 (MFMA) + fused att1 ----------------
    const int gb = bid - SBLK;
    const int wave = tid >> 6;
    const int lane = tid & 63;
    int arow = gb * 64 + wave * 16 + (lane & 15);
    if (arow >= N_NODES) arow = N_NODES - 1;       // clamp for load only
    const float* xp = x + (size_t)arow * F_IN + (lane >> 4) * 8;
    const short8* wp = (const short8*)wf;

    f32x4 acc[4] = {};
    #pragma unroll 4
    for (int kt = 0; kt < NKT; ++kt) {
        f32x4 a0 = *(const f32x4*)(xp + kt * 32);
        f32x4 a1 = *(const f32x4*)(xp + kt * 32 + 4);
        union { short8 s; unsigned short u[8]; } af;
        af.u[0] = f2bf(a0.x); af.u[1] = f2bf(a0.y);
        af.u[2] = f2bf(a0.z); af.u[3] = f2bf(a0.w);
        af.u[4] = f2bf(a1.x); af.u[5] = f2bf(a1.y);
        af.u[6] = f2bf(a1.z); af.u[7] = f2bf(a1.w);
        #pragma unroll
        for (int ct = 0; ct < 4; ++ct) {
            short8 bf = wp[kt * 256 + ct * 64 + lane];
            acc[ct] = __builtin_amdgcn_mfma_f32_16x16x32_bf16(af.s, bf, acc[ct], 0, 0, 0);
        }
    }
    // C/D layout: col = lane&15, row = (lane>>4)*4 + r
    const int lrow_base = wave * 16 + (lane >> 4) * 4;
    const int ocol = lane & 15;
    #pragma unroll
    for (int ct = 0; ct < 4; ++ct) {
        #pragma unroll
        for (int r = 0; r < 4; ++r) {
            int lrow = lrow_base + r;
            int orow = gb * 64 + lrow;
            ls[lrow * 65 + ct * 16 + ocol] = acc[ct][r];
            if (orow < N_NODES)
                h1b[(size_t)orow * HD + ct * 16 + ocol] = f2bf(acc[ct][r]);
        }
    }
    __syncthreads();
    // attention halves: 512 (row,head) tasks over 256 threads
    #pragma unroll
    for (int task = tid; task < 64 * 8; task += 256) {
        int r = task >> 3, h = task & 7;
        int node = gb * 64 + r;
        if (node < N_NODES) {
            float s = 0.f, d = 0.f;
            #pragma unroll
            for (int k = 0; k < 8; ++k) {
                float v = ls[r * 65 + h * 8 + k];
                s += v * a1s[h * 8 + k];
                d += v * a1d[h * 8 + k];
            }
            als[node * 8 + h] = s;
            ald[node * 8 + h] = d;
        }
    }
}

// --- sortcsr: per-bucket LDS counting sort -> csr_src, rowptr, rowcnt -------
__global__ __launch_bounds__(256) void sortcsr_kernel(const int* __restrict__ bcur,
                                                      const int* __restrict__ pairs,
                                                      int* __restrict__ csr_src,
                                                      int* __restrict__ rowptr,
                                                      int* __restrict__ rowcnt) {
    __shared__ int cnt[BS];
    __shared__ int start[BS];
    __shared__ int srcl[ECAP];
    const int tid = threadIdx.x;
    const int lane = tid & 63;
    const int n0 = blockIdx.x * BS;
    const size_t bbase = (size_t)blockIdx.x * ECAP;
    const int* bp = pairs + bbase;
    int ne = bcur[blockIdx.x]; if (ne > ECAP) ne = ECAP;
    if (tid < BS) cnt[tid] = 0;
    __syncthreads();
    for (int k = tid; k < ne; k += 256)
        atomicAdd(&cnt[bp[k] & (BS - 1)], 1);
    __syncthreads();
    if (tid < 64) {
        int a = cnt[lane];
        int xx = a;
        #pragma unroll
        for (int o = 1; o < 64; o <<= 1) { int u = __shfl_up(xx, o, 64); if (lane >= o) xx += u; }
        start[lane] = xx - a;
        cnt[lane] = 0;                                // reuse as cursor
    }
    __syncthreads();
    for (int k = tid; k < ne; k += 256) {
        int v = bp[k];
        int ln = v & (BS - 1);
        int pos = start[ln] + atomicAdd(&cnt[ln], 1);
        srcl[pos] = v >> 6;
    }
    __syncthreads();
    // coalesced writeback + per-node metadata
    for (int k = tid; k < ne; k += 256) csr_src[bbase + k] = srcl[k];
    if (tid < BS) {
        int node = n0 + tid;
        if (node < N_NODES) {
            rowptr[node] = (int)bbase + start[tid];
            rowcnt[node] = cnt[tid];
        }
    }
}

// ---- gather layer 1: flat per-node wave, shfl-dedup p, batched loads --------
__global__ __launch_bounds__(256) void gather1_kernel(
        const int* __restrict__ rowptr, const int* __restrict__ rowcnt,
        const int* __restrict__ csr_src,
        const float* __restrict__ als, const float* __restrict__ ald,
        const unsigned short* __restrict__ h1b, const float* __restrict__ b1,
        const float* __restrict__ W2, const float* __restrict__ a2s,
        const float* __restrict__ a2d,
        unsigned short* __restrict__ g2b, float* __restrict__ al2s,
        float* __restrict__ al2d) {
    int node = (blockIdx.x * 256 + threadIdx.x) >> 6;    // one wave per node
    if (node >= N_NODES) return;
    const int lane = threadIdx.x & 63;
    const int h = lane >> 3;
    const int e8 = lane & 7, base8 = lane & 56;
    const int rs = rowptr[node], ncnt = rowcnt[node];
    const float aldt = ald[node * 8 + h];
    float e = als[node * 8 + h] + aldt;                  // self loop
    e = (e >= 0.f) ? e : 0.2f * e;
    float p = __expf(e);
    float acc = p * bf2f(h1b[(size_t)node * HD + lane]);
    float z = p;
    int k = 0;
    for (; k + 8 <= ncnt; k += 8) {
        int s_own = csr_src[rs + k + e8];                // coalesced 32B/group
        int se[8];
        #pragma unroll
        for (int q = 0; q < 8; ++q) se[q] = __shfl(s_own, base8 | q, 64);
        float ve[8];
        #pragma unroll
        for (int q = 0; q < 8; ++q) ve[q] = bf2f(h1b[(size_t)se[q] * HD + lane]);
        float ee = als[s_own * 8 + h] + aldt;
        ee = (ee >= 0.f) ? ee : 0.2f * ee;
        float pv = __expf(ee);
        #pragma unroll
        for (int q = 0; q < 8; ++q) {
            float pe = __shfl(pv, base8 | q, 64);
            z += pe;
            acc = fmaf(pe, ve[q], acc);
        }
    }
    if (k < ncnt) {                                      // masked final chunk
        const int m = ncnt - k;
        int idx = rs + k + ((e8 < m) ? e8 : (m - 1));
        int s_own = csr_src[idx];
        int se[8];
        #pragma unroll
        for (int q = 0; q < 8; ++q) se[q] = __shfl(s_own, base8 | q, 64);
        float ee = als[s_own * 8 + h] + aldt;
        ee = (ee >= 0.f) ? ee : 0.2f * ee;
        float pv = __expf(ee);
        for (int q = 0; q < m; ++q) {
            float pe = __shfl(pv, base8 | q, 64);
            float ve = bf2f(h1b[(size_t)se[q] * HD + lane]);
            z += pe;
            acc = fmaf(pe, ve, acc);
        }
    }
    // epilogue: alpha-normalize + bias + ELU
    float v = acc / z + b1[lane];
    v = (v > 0.f) ? v : (__expf(v) - 1.f);
    // fused GEMM2: g[c] = sum_j v_j * W2[j][c]  (butterfly over the wave)
    float w[CC];
    #pragma unroll
    for (int c = 0; c < CC; ++c) w[c] = W2[lane * CC + c];
    float g[CC];
    #pragma unroll
    for (int c = 0; c < CC; ++c) {
        float r = v * w[c];
        #pragma unroll
        for (int d = 1; d < 64; d <<= 1) r += __shfl_xor(r, d, 64);
        g[c] = r;
    }
    float s2 = 0.f, d2 = 0.f;
    #pragma unroll
    for (int c = 0; c < CC; ++c) { s2 += g[c] * a2s[c]; d2 += g[c] * a2d[c]; }
    if (lane < CC) g2b[(size_t)node * 8 + lane] = f2bf(g[lane]);
    if (lane == CC) g2b[(size_t)node * 8 + CC] = 0;
    if (lane == 8) al2s[node] = s2;
    if (lane == 9) al2d[node] = d2;
}

// ---- gather layer 2: flat 8-lane groups, shfl-dedup p, log_softmax ----------
__global__ __launch_bounds__(256) void gather2_kernel(
        const int* __restrict__ rowptr, const int* __restrict__ rowcnt,
        const int* __restrict__ csr_src,
        const float* __restrict__ al2s, const float* __restrict__ al2d,
        const unsigned short* __restrict__ g2b, const float* __restrict__ b2,
        float* __restrict__ out) {
    int gid = blockIdx.x * 256 + threadIdx.x;
    int n = gid >> 3, c = gid & 7;
    if (n >= N_NODES) return;
    const int lane = threadIdx.x & 63;
    const int base8 = lane & 56;
    const int rs = rowptr[n], ncnt = rowcnt[n];
    const float adn = al2d[n];
    float e = al2s[n] + adn;                             // self loop
    e = (e >= 0.f) ? e : 0.2f * e;
    float p = __expf(e);
    float acc = p * bf2f(g2b[(size_t)n * 8 + c]);
    float z = p;
    int k = 0;
    for (; k + 8 <= ncnt; k += 8) {
        int s_own = csr_src[rs + k + c];
        int se[8];
        #pragma unroll
        for (int q = 0; q < 8; ++q) se[q] = __shfl(s_own, base8 | q, 64);
        float ve[8];
        #pragma unroll
        for (int q = 0; q < 8; ++q) ve[q] = bf2f(g2b[(size_t)se[q] * 8 + c]);
        float ee = al2s[s_own] + adn;
        ee = (ee >= 0.f) ? ee : 0.2f * ee;
        float pv = __expf(ee);
        #pragma unroll
        for (int q = 0; q < 8; ++q) {
            float pe = __shfl(pv, base8 | q, 64);
            z += pe;
            acc = fmaf(pe, ve[q], acc);
        }
    }
    if (k < ncnt) {
        const int m = ncnt - k;
        int idx = rs + k + ((c < m) ? c : (m - 1));
        int s_own = csr_src[idx];
        int se[8];
        #pragma unroll
        for (int q = 0; q < 8; ++q) se[q] = __shfl(s_own, base8 | q, 64);
        float ee = al2s[s_own] + adn;
        ee = (ee >= 0.f) ? ee : 0.2f * ee;
        float pv = __expf(ee);
        for (int q = 0; q < m; ++q) {
            float pe = __shfl(pv, base8 | q, 64);
            float ve = bf2f(g2b[(size_t)se[q] * 8 + c]);
            z += pe;
            acc = fmaf(pe, ve, acc);
        }
    }
    float o = (c < CC) ? (acc / z + b2[c]) : -1e30f;
    float m2 = o;
    #pragma unroll
    for (int d = 1; d < 8; d <<= 1) m2 = fmaxf(m2, __shfl_xor(m2, d, 8));
    float ex = (c < CC) ? __expf(o - m2) : 0.f;
    float sum = ex;
    #pragma unroll
    for (int d = 1; d < 8; d <<= 1) sum += __shfl_xor(sum, d, 8);
    float lse = m2 + __logf(sum);
    if (c < CC) out[(size_t)n * CC + c] = o - lse;
}

extern "C" void kernel_launch(void* const* d_in, const int* in_sizes, int n_in,
                              void* d_out, int out_size, void* d_ws, size_t ws_size,
                              hipStream_t stream) {
    const float* x   = (const float*)d_in[0];
    const int*   ei  = (const int*)d_in[1];
    const float* W1  = (const float*)d_in[2];
    const float* a1s = (const float*)d_in[3];
    const float* a1d = (const float*)d_in[4];
    const float* b1  = (const float*)d_in[5];
    const float* W2  = (const float*)d_in[6];
    const float* a2s = (const float*)d_in[7];
    const float* a2d = (const float*)d_in[8];
    const float* b2  = (const float*)d_in[9];
    float* out = (float*)d_out;

    // byte-offset workspace allocator (64B aligned)
    char* base = (char*)d_ws;
    size_t off = 0;
    auto alloc = [&](size_t bytes) { char* p = base + off; off = (off + bytes + 63) & ~(size_t)63; return p; };
    unsigned short* h1b = (unsigned short*)alloc((size_t)N_NODES * HD * 2);
    unsigned short* wf  = (unsigned short*)alloc((size_t)W1WORK * 8 * 2);
    float* als  = (float*)alloc((size_t)N_NODES * 8 * 4);
    float* ald  = (float*)alloc((size_t)N_NODES * 8 * 4);
    unsigned short* g2b = (unsigned short*)alloc((size_t)N_NODES * 8 * 2);
    float* al2s = (float*)alloc((size_t)N_NODES * 4);
    float* al2d = (float*)alloc((size_t)N_NODES * 4);
    int* bcur   = (int*)alloc((size_t)NBK * 4);
    int* rowptr = (int*)alloc((size_t)N_NODES * 4);
    int* rowcnt = (int*)alloc((size_t)N_NODES * 4);
    int* csr_src= (int*)alloc((size_t)NBK * ECAP * 4);
    int* pairs  = (int*)alloc((size_t)NBK * ECAP * 4);   // packed (s<<6)|ln

    prep_kernel<<<17, 256, 0, stream>>>(W1, wf, bcur);
    fused_kernel<<<SBLK + GEMMBLKS, 256, 0, stream>>>(
        ei, bcur, pairs, x, wf, a1s, a1d, h1b, als, ald);
    sortcsr_kernel<<<NBK, 256, 0, stream>>>(bcur, pairs, csr_src, rowptr, rowcnt);
    gather1_kernel<<<(N_NODES * 64 + 255) / 256, 256, 0, stream>>>(
        rowptr, rowcnt, csr_src, als, ald, h1b, b1, W2, a2s, a2d, g2b, al2s, al2d);
    gather2_kernel<<<(N_NODES * 8 + 255) / 256, 256, 0, stream>>>(
        rowptr, rowcnt, csr_src, al2s, al2d, g2b, b2, out);
}